// Round 20
// baseline (184.140 us; speedup 1.0000x reference)
//
#include <hip/hip_runtime.h>
#include <hip/hip_bf16.h>

#define BB 2
#define II 1024
#define JJ 1024
#define DD 512
#define PP 64
#define HH 8
#define CC 32
#define HC 256
#define INFF 1.0e9f
#define EPSF 1e-5f

typedef unsigned int u32;
typedef unsigned short u16;
typedef __attribute__((ext_vector_type(8))) short short8;
typedef __attribute__((ext_vector_type(4))) float f32x4;
typedef __attribute__((ext_vector_type(4))) float f4v;
typedef __attribute__((ext_vector_type(2))) unsigned int u32x2;

#define MFMA16(a,b,c) __builtin_amdgcn_mfma_f32_16x16x32_bf16(a,b,c,0,0,0)

__device__ inline float bf16lo(u32 u){ u32 x = u << 16; float f; __builtin_memcpy(&f,&x,4); return f; }
__device__ inline float bf16hi(u32 u){ u32 x = u & 0xFFFF0000u; float f; __builtin_memcpy(&f,&x,4); return f; }
__device__ inline float bf16s(u16 h){ u32 x = ((u32)h) << 16; float f; __builtin_memcpy(&f,&x,4); return f; }
__device__ inline u32 pk2(float a, float b){
    __hip_bfloat162 h2 = __float22bfloat162_rn(float2{a, b});
    u32 r; __builtin_memcpy(&r, &h2, 4); return r;
}
__device__ inline u16 f2bf(float f){
    __hip_bfloat16 h = __float2bfloat16(f);
    u16 r; __builtin_memcpy(&r, &h, 2); return r;
}
__device__ inline float sigmoidf_(float x){ return 1.0f/(1.0f + __expf(-x)); }
__device__ inline short8 ld_frag16(const u16* p){ short8 v; __builtin_memcpy(&v, p, 16); return v; }
__device__ inline f4v ntld4(const float* p){ return __builtin_nontemporal_load((const f4v*)p); }

// ---------------- K1: LayerNorm + prep (gwb16/gac, wb16, wo16) ----------------
__global__ __launch_bounds__(128) void ln_kernel(
    const float* __restrict__ xi, const float* __restrict__ xj,
    const float* __restrict__ gi, const float* __restrict__ bi,
    const float* __restrict__ gj, const float* __restrict__ bj,
    const float* __restrict__ lng, const float* __restrict__ lnb,
    const float* __restrict__ Wp, const float* __restrict__ Wpg,
    const float* __restrict__ Wq, const float* __restrict__ Wk,
    const float* __restrict__ Wv, const float* __restrict__ Wg,
    const float* __restrict__ Wo,
    float* __restrict__ ni, u16* __restrict__ ni16, u16* __restrict__ nj16,
    u16* __restrict__ gwb16, float* __restrict__ gac,
    u16* __restrict__ wb16, u16* __restrict__ wo16)
{
    const float qscale = 0.17677669529663687f;   // 1/sqrt(32)
    if (blockIdx.x == 4096){
        int t = threadIdx.x;
        #pragma unroll
        for (int e = 0; e < 8; ++e){
            int idx = t*8 + e;              // 0..1023
            int ee = idx & 7, nn = (idx >> 3) & 15, gg = (idx >> 7) & 3, ch = (idx >> 9) & 1;
            int k = ch*32 + gg*8 + ee;
            float wv = lng[k] * ((nn < 8) ? Wp[k*8 + nn] : Wpg[k*8 + (nn-8)]);
            gwb16[idx] = f2bf(wv);
        }
        if (t < 32){
            int c = t & 15;
            float acc2 = 0.f;
            for (int p = 0; p < 64; ++p){
                float wv = (c < 8) ? Wp[p*8+c] : Wpg[p*8+(c-8)];
                acc2 += wv * ((t < 16) ? lng[p] : lnb[p]);
            }
            gac[t] = acc2;                  // [0..15]=A, [16..31]=C
        }
        return;
    }
    if (blockIdx.x >= 4609){
        // Wo conversion -> B-frag layout wo16[((ks*4+grp)*512 + n)*8 + e], k = ks*32+grp*8+e
        int wb = blockIdx.x - 4609;         // 0..127
        int t = threadIdx.x;
        int idx0 = wb*1024 + t*8;
        int n = (idx0 >> 3) & 511, grp = (idx0 >> 12) & 3, ks = idx0 >> 14;
        int kb = ks*32 + grp*8;
        u16 outv[8];
        #pragma unroll
        for (int e = 0; e < 8; ++e)
            outv[e] = f2bf(Wo[(size_t)(kb + e)*DD + n]);
        *(uint4*)&wo16[idx0] = *(uint4*)outv;
        return;
    }
    if (blockIdx.x > 4096){
        // W{q,k,v,g} conversion -> wb16[(((z*16+ks)*4+grp)*256 + n)*8 + e]
        int wb = blockIdx.x - 4097;         // 0..511
        int t = threadIdx.x;
        int idx0 = wb*1024 + t*8;
        int n = (idx0 >> 3) & 255, grp = (idx0 >> 11) & 3;
        int ks = (idx0 >> 13) & 15, z = idx0 >> 17;
        const float* Wsrc = (z==0)?Wq : (z==1)?Wk : (z==2)?Wv : Wg;
        int kbase2 = ks*32 + grp*8;
        u16 outv[8];
        #pragma unroll
        for (int e = 0; e < 8; ++e){
            float wv = Wsrc[(size_t)(kbase2 + e)*HC + n];
            if (z == 0) wv *= qscale;
            outv[e] = f2bf(wv);
        }
        *(uint4*)&wb16[idx0] = *(uint4*)outv;
        return;
    }
    int row = blockIdx.x;           // 0..4095
    int side = row >> 11;
    int r = row & 2047;
    const float* x = (side ? xj : xi) + (size_t)r * DD;
    const float* gg = side ? gj : gi;
    const float* bbp = side ? bj : bi;
    int t = threadIdx.x;
    float4 v = ((const float4*)x)[t];
    float s  = v.x + v.y + v.z + v.w;
    float sq = v.x*v.x + v.y*v.y + v.z*v.z + v.w*v.w;
    #pragma unroll
    for (int off = 32; off; off >>= 1){ s += __shfl_down(s, off); sq += __shfl_down(sq, off); }
    __shared__ float ls[2], lq[2];
    int w = t >> 6, lane = t & 63;
    if (lane == 0){ ls[w] = s; lq[w] = sq; }
    __syncthreads();
    s = ls[0] + ls[1]; sq = lq[0] + lq[1];
    float mean = s * (1.0f/DD);
    float var  = sq * (1.0f/DD) - mean*mean;
    float rstd = rsqrtf(var + EPSF);
    float4 gv = ((const float4*)gg)[t];
    float4 bv = ((const float4*)bbp)[t];
    float4 o;
    o.x = (v.x-mean)*rstd*gv.x + bv.x;
    o.y = (v.y-mean)*rstd*gv.y + bv.y;
    o.z = (v.z-mean)*rstd*gv.z + bv.z;
    o.w = (v.w-mean)*rstd*gv.w + bv.w;
    if (!side) ((float4*)(ni + (size_t)r*DD))[t] = o;
    u16* x16 = (side ? nj16 : ni16) + (size_t)r*DD;
    uint2 pk; pk.x = pk2(o.x, o.y); pk.y = pk2(o.z, o.w);
    *(uint2*)&x16[t*4] = pk;
}

// ---------------- K2: combo — bias (MFMA stream, NT load+store) + proj (MFMA GEMM) ----------------
__global__ __launch_bounds__(256) void combo_kernel(
    const float* __restrict__ pe, const float* __restrict__ pmask,
    const u16* __restrict__ gwb16, const float* __restrict__ gac,
    const float* __restrict__ bp, const float* __restrict__ bpg,
    u16* __restrict__ sc,
    const u16* __restrict__ ni16, const u16* __restrict__ nj16,
    const u16* __restrict__ wb16, const float* __restrict__ bg,
    u16* __restrict__ qbf, u16* __restrict__ kbf,
    u16* __restrict__ vT, float* __restrict__ g)
{
    int n = blockIdx.x;
    int q5 = n / 5, r5 = n - q5*5;
    int t = threadIdx.x;
    int wid = t >> 6, lane = t & 63;
    int ln15 = lane & 15, grp = lane >> 4;
    const f32x4 zeroc = {0.f,0.f,0.f,0.f};

    if (r5 != 4){
        // ---------- bias body (NT pe loads, NT sc stores) ----------
        int bi = n - q5;                           // 0..2047  (b*1024 + i)
        const size_t peRow = (size_t)bi * JJ * PP;
        int r4 = lane >> 2, q4 = lane & 3;
        short8 bf0 = ld_frag16(gwb16 + ((0*4 + grp)*16 + ln15)*8);
        short8 bf1 = ld_frag16(gwb16 + ((1*4 + grp)*16 + ln15)*8);
        float Acoef = gac[ln15];
        float Ccoef = gac[16 + ln15];
        float bpv  = bp[ln15 & 7];
        float bpgv = bpg[ln15 & 7];
        size_t scb = (size_t)bi * HH * JJ;
        const float* wbase = pe + peRow + (size_t)(wid*256) * PP + r4*64 + q4*4;
        const float* mbase = pmask + (size_t)bi*JJ + wid*256 + r4;
        int selg = grp >> 1;
        int idx0 = 4*ln15 + 2*(grp & 1);

        for (int tile = 0; tile < 16; ++tile){
            const float* pt = wbase + (size_t)tile*1024;
            f4v F0 = ntld4(pt + 0);
            f4v F1 = ntld4(pt + 16);
            f4v F2 = ntld4(pt + 32);
            f4v F3 = ntld4(pt + 48);
            float pmv = mbase[tile*16];
            float s  = (F0.x+F0.y+F0.z+F0.w) + (F1.x+F1.y+F1.z+F1.w)
                     + (F2.x+F2.y+F2.z+F2.w) + (F3.x+F3.y+F3.z+F3.w);
            float sq = F0.x*F0.x+F0.y*F0.y+F0.z*F0.z+F0.w*F0.w
                     + F1.x*F1.x+F1.y*F1.y+F1.z*F1.z+F1.w*F1.w
                     + F2.x*F2.x+F2.y*F2.y+F2.z*F2.z+F2.w*F2.w
                     + F3.x*F3.x+F3.y*F3.y+F3.z*F3.z+F3.w*F3.w;
            s  += __shfl_xor(s, 1);  s  += __shfl_xor(s, 2);
            sq += __shfl_xor(sq, 1); sq += __shfl_xor(sq, 2);
            u32 W00 = pk2(F0.x,F0.y), W01 = pk2(F0.z,F0.w);
            u32 W10 = pk2(F1.x,F1.y), W11 = pk2(F1.z,F1.w);
            u32 W20 = pk2(F2.x,F2.y), W21 = pk2(F2.z,F2.w);
            u32 W30 = pk2(F3.x,F3.y), W31 = pk2(F3.z,F3.w);
            u32 Wa0 = selg ? W10 : W00, Wa1 = selg ? W11 : W01;
            u32 Wb0 = selg ? W30 : W20, Wb1 = selg ? W31 : W21;
            u32 aw[4];
            aw[0] = __shfl(Wa0, idx0);     aw[1] = __shfl(Wa1, idx0);
            aw[2] = __shfl(Wa0, idx0 + 1); aw[3] = __shfl(Wa1, idx0 + 1);
            short8 a0; __builtin_memcpy(&a0, aw, 16);
            aw[0] = __shfl(Wb0, idx0);     aw[1] = __shfl(Wb1, idx0);
            aw[2] = __shfl(Wb0, idx0 + 1); aw[3] = __shfl(Wb1, idx0 + 1);
            short8 a1; __builtin_memcpy(&a1, aw, 16);
            f32x4 acc = MFMA16(a0, bf0, zeroc);
            acc = MFMA16(a1, bf1, acc);        // acc[r] = S[j0+grp*4+r][c=ln15]
            int j0 = wid*256 + tile*16;
            float pbq[4];
            #pragma unroll
            for (int r = 0; r < 4; ++r){
                int sl = 16*grp + 4*r;
                float mean = __shfl(s,  sl) * (1.0f/PP);
                float msq  = __shfl(sq, sl) * (1.0f/PP);
                float rstd = rsqrtf(msq - mean*mean + EPSF);
                float afull = rstd*(acc[r] - mean*Acoef) + Ccoef;
                float other = __shfl_xor(afull, 8);
                float mbv = INFF * (__shfl(pmv, sl) - 1.0f);
                pbq[r] = (afull + bpv) * sigmoidf_(other + bpgv) + mbv;
            }
            if (ln15 < 8){
                u32x2 st;
                st.x = pk2(pbq[0], pbq[1]);
                st.y = pk2(pbq[2], pbq[3]);
                __builtin_nontemporal_store(st, (u32x2*)&sc[scb + (size_t)ln15*JJ + j0 + grp*4]);
            }
        }
    } else {
        // ---------- proj body: MFMA GEMM, no LDS, no barriers ----------
        int pid = q5;                              // 0..511
        int z = pid & 3, ct = (pid >> 2) & 3, rt = pid >> 4;
        const u16* X16 = (z==1 || z==2) ? nj16 : ni16;
        int row0 = rt*64, c0 = ct*64;
        int rowb = row0 + wid*16;
        const u16* xrow = X16 + (size_t)(rowb + ln15)*DD;
        const u16* wz = wb16 + (size_t)z*16*4*256*8;
        f32x4 acc0 = zeroc, acc1 = zeroc, acc2 = zeroc, acc3 = zeroc;
        for (int ks = 0; ks < 16; ++ks){
            short8 af = ld_frag16(xrow + ks*32 + grp*8);
            const u16* wk2 = wz + ((size_t)(ks*4 + grp)*256)*8;
            short8 b0 = ld_frag16(wk2 + (c0 + 0*16 + ln15)*8);
            short8 b1 = ld_frag16(wk2 + (c0 + 1*16 + ln15)*8);
            short8 b2 = ld_frag16(wk2 + (c0 + 2*16 + ln15)*8);
            short8 b3 = ld_frag16(wk2 + (c0 + 3*16 + ln15)*8);
            acc0 = MFMA16(af, b0, acc0);
            acc1 = MFMA16(af, b1, acc1);
            acc2 = MFMA16(af, b2, acc2);
            acc3 = MFMA16(af, b3, acc3);
        }
        int b = rowb >> 10, ij0 = (rowb & 1023) + grp*4;
        if (z == 2){
            #pragma unroll
            for (int cf = 0; cf < 4; ++cf){
                f32x4 a = (cf==0)?acc0:(cf==1)?acc1:(cf==2)?acc2:acc3;
                int chc = c0 + cf*16 + ln15;
                int h = chc >> 5, c = chc & 31;
                uint2 st;
                st.x = pk2(a[0], a[1]);
                st.y = pk2(a[2], a[3]);
                *(uint2*)&vT[((size_t)(b*HH + h)*CC + c)*JJ + ij0] = st;
            }
        } else if (z == 3){
            float bgv[4];
            #pragma unroll
            for (int cf = 0; cf < 4; ++cf) bgv[cf] = bg[c0 + cf*16 + ln15];
            #pragma unroll
            for (int cf = 0; cf < 4; ++cf){
                f32x4 a = (cf==0)?acc0:(cf==1)?acc1:(cf==2)?acc2:acc3;
                int chc = c0 + cf*16 + ln15;
                #pragma unroll
                for (int r = 0; r < 4; ++r){
                    int row = rowb + grp*4 + r;
                    g[(size_t)row*HC + chc] = sigmoidf_(a[r] + bgv[cf]);
                }
            }
        } else {
            u16* dstb = (z == 0) ? qbf : kbf;
            #pragma unroll
            for (int cf = 0; cf < 4; ++cf){
                f32x4 a = (cf==0)?acc0:(cf==1)?acc1:(cf==2)?acc2:acc3;
                int chc = c0 + cf*16 + ln15;
                int h = chc >> 5, c = chc & 31;
                #pragma unroll
                for (int r = 0; r < 4; ++r){
                    dstb[((size_t)(b*HH + h)*II + ij0 + r)*CC + c] = f2bf(a[r]);
                }
            }
        }
    }
}

// ---------------- K3: fused flash attention (parallel 4-wave epilogue, bf16 o) ----------------
__global__ __launch_bounds__(256) void fattn_kernel(
    const u16* __restrict__ qbf, const u16* __restrict__ kbf,
    const u16* __restrict__ vT, const u16* __restrict__ sc,
    const float* __restrict__ g, u16* __restrict__ o16)
{
    int it = blockIdx.x, h = blockIdx.y, b = blockIdx.z;
    int t = threadIdx.x;
    int w = t >> 6, lane = t & 63;       // jw = w (0..3)
    int ln15 = lane & 15, grp = lane >> 4;
    int i0 = it*16;
    size_t bh = (size_t)(b*HH + h);

    short8 qf = ld_frag16(qbf + (bh*II + i0 + ln15)*CC + grp*8);
    const u16* kbase = kbf + bh*JJ*CC;
    const u16* vbase = vT + bh*CC*JJ;
    size_t scb = ((size_t)(b*II + i0 + ln15)*HH + h)*JJ;

    f32x4 oacc0 = {0.f,0.f,0.f,0.f}, oacc1 = {0.f,0.f,0.f,0.f};
    float m = -INFINITY, l = 0.f;
    const f32x4 zeroc = {0.f,0.f,0.f,0.f};

    for (int ch = 0; ch < 8; ++ch){
        int j0 = (ch*4 + w)*32;
        short8 ka0 = ld_frag16(kbase + (size_t)(j0 + ln15)*CC + grp*8);
        short8 ka1 = ld_frag16(kbase + (size_t)(j0 + 16 + ln15)*CC + grp*8);
        f32x4 s0 = MFMA16(ka0, qf, zeroc);   // S[j0+grp*4+r][i0+ln15]
        f32x4 s1 = MFMA16(ka1, qf, zeroc);
        uint2 b0 = *(const uint2*)&sc[scb + j0 + grp*4];
        uint2 b1 = *(const uint2*)&sc[scb + j0 + 16 + grp*4];
        float s[8];
        s[0] = s0[0] + bf16lo(b0.x); s[1] = s0[1] + bf16hi(b0.x);
        s[2] = s0[2] + bf16lo(b0.y); s[3] = s0[3] + bf16hi(b0.y);
        s[4] = s1[0] + bf16lo(b1.x); s[5] = s1[1] + bf16hi(b1.x);
        s[6] = s1[2] + bf16lo(b1.y); s[7] = s1[3] + bf16hi(b1.y);
        float pm = s[0];
        #pragma unroll
        for (int e = 1; e < 8; ++e) pm = fmaxf(pm, s[e]);
        pm = fmaxf(pm, __shfl_xor(pm, 16));
        pm = fmaxf(pm, __shfl_xor(pm, 32));
        float mn = fmaxf(m, pm);
        float alpha = __expf(m - mn);
        m = mn;
        float p[8], psum = 0.f;
        #pragma unroll
        for (int e = 0; e < 8; ++e){ p[e] = __expf(s[e] - m); psum += p[e]; }
        l = l*alpha + psum;
        #pragma unroll
        for (int r = 0; r < 4; ++r){
            float ar = __shfl(alpha, grp*4 + r);
            oacc0[r] *= ar; oacc1[r] *= ar;
        }
        u32 pw[4];
        pw[0] = pk2(p[0], p[1]); pw[1] = pk2(p[2], p[3]);
        pw[2] = pk2(p[4], p[5]); pw[3] = pk2(p[6], p[7]);
        short8 pa; __builtin_memcpy(&pa, pw, 16);
        const u16* vr0 = vbase + (size_t)(ln15)*JJ + j0 + grp*4;
        const u16* vr1 = vbase + (size_t)(16 + ln15)*JJ + j0 + grp*4;
        uint2 va0 = *(const uint2*)vr0, va1 = *(const uint2*)(vr0 + 16);
        u32 vw[4] = {va0.x, va0.y, va1.x, va1.y};
        short8 vb0; __builtin_memcpy(&vb0, vw, 16);
        uint2 vc0 = *(const uint2*)vr1, vc1 = *(const uint2*)(vr1 + 16);
        u32 vx[4] = {vc0.x, vc0.y, vc1.x, vc1.y};
        short8 vb1; __builtin_memcpy(&vb1, vx, 16);
        oacc0 = MFMA16(pa, vb0, oacc0);
        oacc1 = MFMA16(pa, vb1, oacc1);
    }
    l += __shfl_xor(l, 16); l += __shfl_xor(l, 32);

    __shared__ float mb[4][64], lb[4][64], ob[4][8][64];
    mb[w][lane] = m; lb[w][lane] = l;
    #pragma unroll
    for (int r = 0; r < 4; ++r){ ob[w][r][lane] = oacc0[r]; ob[w][4+r][lane] = oacc1[r]; }
    __syncthreads();
    {
        int r = w;                           // each wave merges one r (4x parallel)
        int row = grp*4 + r;                 // 0..15
        float M = fmaxf(fmaxf(mb[0][row], mb[1][row]), fmaxf(mb[2][row], mb[3][row]));
        float sw[4], L = 0.f;
        #pragma unroll
        for (int w2 = 0; w2 < 4; ++w2){
            sw[w2] = __expf(mb[w2][row] - M);
            L += lb[w2][row] * sw[w2];
        }
        float inv = 1.0f / L;
        float o0 = 0.f, o1 = 0.f;
        #pragma unroll
        for (int w2 = 0; w2 < 4; ++w2){
            o0 += ob[w2][r][lane]   * sw[w2];
            o1 += ob[w2][4+r][lane] * sw[w2];
        }
        size_t rb = (size_t)(b*II + i0 + row)*HC + h*CC;
        o16[rb + ln15]      = f2bf(o0 * inv * g[rb + ln15]);
        o16[rb + 16 + ln15] = f2bf(o1 * inv * g[rb + 16 + ln15]);
    }
}

// ---------------- K4: out = ni + (o16 @ Wo + bo) * mask  (MFMA, LDS-free) ----------------
__global__ __launch_bounds__(256) void out_mfma(
    const u16* __restrict__ o16, const u16* __restrict__ wo16,
    const float* __restrict__ bo, const float* __restrict__ ni,
    const float* __restrict__ nmask, float* __restrict__ out)
{
    int rt = blockIdx.x, ct = blockIdx.y;      // 32 x 8
    int t = threadIdx.x;
    int wid = t >> 6, lane = t & 63;
    int ln15 = lane & 15, grp = lane >> 4;
    const f32x4 zeroc = {0.f,0.f,0.f,0.f};
    int rowb = rt*64 + wid*16, c0 = ct*64;
    const u16* xrow = o16 + (size_t)(rowb + ln15)*HC;
    f32x4 acc0 = zeroc, acc1 = zeroc, acc2 = zeroc, acc3 = zeroc;
    for (int ks = 0; ks < 8; ++ks){
        short8 af = ld_frag16(xrow + ks*32 + grp*8);
        const u16* wk2 = wo16 + ((size_t)(ks*4 + grp)*DD)*8;
        short8 b0 = ld_frag16(wk2 + (c0 + 0*16 + ln15)*8);
        short8 b1 = ld_frag16(wk2 + (c0 + 1*16 + ln15)*8);
        short8 b2 = ld_frag16(wk2 + (c0 + 2*16 + ln15)*8);
        short8 b3 = ld_frag16(wk2 + (c0 + 3*16 + ln15)*8);
        acc0 = MFMA16(af, b0, acc0);
        acc1 = MFMA16(af, b1, acc1);
        acc2 = MFMA16(af, b2, acc2);
        acc3 = MFMA16(af, b3, acc3);
    }
    float msk[4], niv;
    #pragma unroll
    for (int r = 0; r < 4; ++r) msk[r] = nmask[rowb + grp*4 + r];
    #pragma unroll
    for (int cf = 0; cf < 4; ++cf){
        f32x4 a = (cf==0)?acc0:(cf==1)?acc1:(cf==2)?acc2:acc3;
        int chc = c0 + cf*16 + ln15;
        float bov = bo[chc];
        #pragma unroll
        for (int r = 0; r < 4; ++r){
            int row = rowb + grp*4 + r;
            niv = ni[(size_t)row*DD + chc];
            out[(size_t)row*DD + chc] = (a[r] + bov)*msk[r] + niv;
        }
    }
}

extern "C" void kernel_launch(void* const* d_in, const int* in_sizes, int n_in,
                              void* d_out, int out_size, void* d_ws, size_t ws_size,
                              hipStream_t stream)
{
    const float* node_i = (const float*)d_in[0];
    const float* node_j = (const float*)d_in[1];
    const float* pe     = (const float*)d_in[2];
    const float* pmask  = (const float*)d_in[3];
    const float* nmask  = (const float*)d_in[4];
    const float* ln_i_g = (const float*)d_in[5];
    const float* ln_i_b = (const float*)d_in[6];
    const float* ln_j_g = (const float*)d_in[7];
    const float* ln_j_b = (const float*)d_in[8];
    const float* ln_p_g = (const float*)d_in[9];
    const float* ln_p_b = (const float*)d_in[10];
    const float* Wp     = (const float*)d_in[11];
    const float* bp     = (const float*)d_in[12];
    const float* Wpg    = (const float*)d_in[13];
    const float* bpg    = (const float*)d_in[14];
    const float* Wq     = (const float*)d_in[15];
    const float* Wk     = (const float*)d_in[16];
    const float* Wv     = (const float*)d_in[17];
    const float* Wg     = (const float*)d_in[18];
    const float* bg     = (const float*)d_in[19];
    const float* Wo     = (const float*)d_in[20];
    const float* bo     = (const float*)d_in[21];
    float* out = (float*)d_out;

    char* ws = (char*)d_ws;
    float* ni    = (float*)(ws + 0);                     // 4 MB  (f32, residual)
    u16*   ni16  = (u16*)  (ws + ((size_t)4<<20));       // 2 MB
    u16*   nj16  = (u16*)  (ws + ((size_t)6<<20));       // 2 MB
    u16*   qbf   = (u16*)  (ws + ((size_t)8<<20));       // 1 MB
    u16*   kbf   = (u16*)  (ws + ((size_t)9<<20));       // 1 MB
    u16*   vTb   = (u16*)  (ws + ((size_t)10<<20));      // 1 MB
    u16*   gwb16 = (u16*)  (ws + ((size_t)11<<20));      // 2 KB
    float* gac   = (float*)(ws + ((size_t)11<<20) + 4096); // 128 B
    u16*   wb16  = (u16*)  (ws + ((size_t)12<<20));      // 1 MB
    u16*   wo16  = (u16*)  (ws + ((size_t)13<<20));      // 256 KB
    float* g     = (float*)(ws + ((size_t)14<<20));      // 2 MB
    u16*   o16   = (u16*)  (ws + ((size_t)16<<20));      // 1 MB
    u16*   sc    = (u16*)  (ws + ((size_t)18<<20));      // 32 MB

    ln_kernel<<<dim3(4737), dim3(128), 0, stream>>>(
        node_i, node_j, ln_i_g, ln_i_b, ln_j_g, ln_j_b,
        ln_p_g, ln_p_b, Wp, Wpg, Wq, Wk, Wv, Wg, Wo,
        ni, ni16, nj16, gwb16, gac, wb16, wo16);
    combo_kernel<<<dim3(2560), dim3(256), 0, stream>>>(
        pe, pmask, gwb16, gac, bp, bpg, sc,
        ni16, nj16, wb16, bg, qbf, kbf, vTb, g);
    fattn_kernel<<<dim3(64,8,2), dim3(256), 0, stream>>>(qbf, kbf, vTb, sc, g, o16);
    out_mfma<<<dim3(32,8), dim3(256), 0, stream>>>(o16, wo16, bo, ni, nmask, out);
}

// Round 21
// 176.975 us; speedup vs baseline: 1.0405x; 1.0405x over previous
//
#include <hip/hip_runtime.h>
#include <hip/hip_bf16.h>

#define BB 2
#define II 1024
#define JJ 1024
#define DD 512
#define PP 64
#define HH 8
#define CC 32
#define HC 256
#define INFF 1.0e9f
#define EPSF 1e-5f

typedef unsigned int u32;
typedef unsigned short u16;
typedef __attribute__((ext_vector_type(8))) short short8;
typedef __attribute__((ext_vector_type(4))) float f32x4;
typedef __attribute__((ext_vector_type(4))) float f4v;

#define MFMA16(a,b,c) __builtin_amdgcn_mfma_f32_16x16x32_bf16(a,b,c,0,0,0)

__device__ inline float bf16lo(u32 u){ u32 x = u << 16; float f; __builtin_memcpy(&f,&x,4); return f; }
__device__ inline float bf16hi(u32 u){ u32 x = u & 0xFFFF0000u; float f; __builtin_memcpy(&f,&x,4); return f; }
__device__ inline float bf16s(u16 h){ u32 x = ((u32)h) << 16; float f; __builtin_memcpy(&f,&x,4); return f; }
__device__ inline u32 pk2(float a, float b){
    __hip_bfloat162 h2 = __float22bfloat162_rn(float2{a, b});
    u32 r; __builtin_memcpy(&r, &h2, 4); return r;
}
__device__ inline u16 f2bf(float f){
    __hip_bfloat16 h = __float2bfloat16(f);
    u16 r; __builtin_memcpy(&r, &h, 2); return r;
}
__device__ inline float sigmoidf_(float x){ return 1.0f/(1.0f + __expf(-x)); }
__device__ inline short8 ld_frag16(const u16* p){ short8 v; __builtin_memcpy(&v, p, 16); return v; }
__device__ inline f4v ntld4(const float* p){ return __builtin_nontemporal_load((const f4v*)p); }

// ---------------- K1: LayerNorm + prep (gwb16/gac, wb16, wo16) ----------------
__global__ __launch_bounds__(128) void ln_kernel(
    const float* __restrict__ xi, const float* __restrict__ xj,
    const float* __restrict__ gi, const float* __restrict__ bi,
    const float* __restrict__ gj, const float* __restrict__ bj,
    const float* __restrict__ lng, const float* __restrict__ lnb,
    const float* __restrict__ Wp, const float* __restrict__ Wpg,
    const float* __restrict__ Wq, const float* __restrict__ Wk,
    const float* __restrict__ Wv, const float* __restrict__ Wg,
    const float* __restrict__ Wo,
    float* __restrict__ ni, u16* __restrict__ ni16, u16* __restrict__ nj16,
    u16* __restrict__ gwb16, float* __restrict__ gac,
    u16* __restrict__ wb16, u16* __restrict__ wo16)
{
    const float qscale = 0.17677669529663687f;   // 1/sqrt(32)
    if (blockIdx.x == 4096){
        int t = threadIdx.x;
        #pragma unroll
        for (int e = 0; e < 8; ++e){
            int idx = t*8 + e;              // 0..1023
            int ee = idx & 7, nn = (idx >> 3) & 15, gg = (idx >> 7) & 3, ch = (idx >> 9) & 1;
            int k = ch*32 + gg*8 + ee;
            float wv = lng[k] * ((nn < 8) ? Wp[k*8 + nn] : Wpg[k*8 + (nn-8)]);
            gwb16[idx] = f2bf(wv);
        }
        if (t < 32){
            int c = t & 15;
            float acc2 = 0.f;
            for (int p = 0; p < 64; ++p){
                float wv = (c < 8) ? Wp[p*8+c] : Wpg[p*8+(c-8)];
                acc2 += wv * ((t < 16) ? lng[p] : lnb[p]);
            }
            gac[t] = acc2;                  // [0..15]=A, [16..31]=C
        }
        return;
    }
    if (blockIdx.x >= 4609){
        // Wo conversion -> B-frag layout wo16[((ks*4+grp)*512 + n)*8 + e], k = ks*32+grp*8+e
        int wb = blockIdx.x - 4609;         // 0..127
        int t = threadIdx.x;
        int idx0 = wb*1024 + t*8;
        int n = (idx0 >> 3) & 511, grp = (idx0 >> 12) & 3, ks = idx0 >> 14;
        int kb = ks*32 + grp*8;
        u16 outv[8];
        #pragma unroll
        for (int e = 0; e < 8; ++e)
            outv[e] = f2bf(Wo[(size_t)(kb + e)*DD + n]);
        *(uint4*)&wo16[idx0] = *(uint4*)outv;
        return;
    }
    if (blockIdx.x > 4096){
        // W{q,k,v,g} conversion -> wb16[(((z*16+ks)*4+grp)*256 + n)*8 + e]
        int wb = blockIdx.x - 4097;         // 0..511
        int t = threadIdx.x;
        int idx0 = wb*1024 + t*8;
        int n = (idx0 >> 3) & 255, grp = (idx0 >> 11) & 3;
        int ks = (idx0 >> 13) & 15, z = idx0 >> 17;
        const float* Wsrc = (z==0)?Wq : (z==1)?Wk : (z==2)?Wv : Wg;
        int kbase2 = ks*32 + grp*8;
        u16 outv[8];
        #pragma unroll
        for (int e = 0; e < 8; ++e){
            float wv = Wsrc[(size_t)(kbase2 + e)*HC + n];
            if (z == 0) wv *= qscale;
            outv[e] = f2bf(wv);
        }
        *(uint4*)&wb16[idx0] = *(uint4*)outv;
        return;
    }
    int row = blockIdx.x;           // 0..4095
    int side = row >> 11;
    int r = row & 2047;
    const float* x = (side ? xj : xi) + (size_t)r * DD;
    const float* gg = side ? gj : gi;
    const float* bbp = side ? bj : bi;
    int t = threadIdx.x;
    float4 v = ((const float4*)x)[t];
    float s  = v.x + v.y + v.z + v.w;
    float sq = v.x*v.x + v.y*v.y + v.z*v.z + v.w*v.w;
    #pragma unroll
    for (int off = 32; off; off >>= 1){ s += __shfl_down(s, off); sq += __shfl_down(sq, off); }
    __shared__ float ls[2], lq[2];
    int w = t >> 6, lane = t & 63;
    if (lane == 0){ ls[w] = s; lq[w] = sq; }
    __syncthreads();
    s = ls[0] + ls[1]; sq = lq[0] + lq[1];
    float mean = s * (1.0f/DD);
    float var  = sq * (1.0f/DD) - mean*mean;
    float rstd = rsqrtf(var + EPSF);
    float4 gv = ((const float4*)gg)[t];
    float4 bv = ((const float4*)bbp)[t];
    float4 o;
    o.x = (v.x-mean)*rstd*gv.x + bv.x;
    o.y = (v.y-mean)*rstd*gv.y + bv.y;
    o.z = (v.z-mean)*rstd*gv.z + bv.z;
    o.w = (v.w-mean)*rstd*gv.w + bv.w;
    if (!side) ((float4*)(ni + (size_t)r*DD))[t] = o;
    u16* x16 = (side ? nj16 : ni16) + (size_t)r*DD;
    uint2 pk; pk.x = pk2(o.x, o.y); pk.y = pk2(o.z, o.w);
    *(uint2*)&x16[t*4] = pk;
}

// ---------------- K2: combo — bias (MFMA stream, NT loads, coalesced sc) + proj (MFMA GEMM) ----------------
// sc layout: [bi][jblk = j/16][h][j%16]  (per-wave tile store = 256 B contiguous)
__global__ __launch_bounds__(256) void combo_kernel(
    const float* __restrict__ pe, const float* __restrict__ pmask,
    const u16* __restrict__ gwb16, const float* __restrict__ gac,
    const float* __restrict__ bp, const float* __restrict__ bpg,
    u16* __restrict__ sc,
    const u16* __restrict__ ni16, const u16* __restrict__ nj16,
    const u16* __restrict__ wb16, const float* __restrict__ bg,
    u16* __restrict__ qbf, u16* __restrict__ kbf,
    u16* __restrict__ vT, float* __restrict__ g)
{
    int n = blockIdx.x;
    int q5 = n / 5, r5 = n - q5*5;
    int t = threadIdx.x;
    int wid = t >> 6, lane = t & 63;
    int ln15 = lane & 15, grp = lane >> 4;
    const f32x4 zeroc = {0.f,0.f,0.f,0.f};

    if (r5 != 4){
        // ---------- bias body (NT pe loads, coalesced sc stores) ----------
        int bi = n - q5;                           // 0..2047  (b*1024 + i)
        const size_t peRow = (size_t)bi * JJ * PP;
        int r4 = lane >> 2, q4 = lane & 3;
        short8 bf0 = ld_frag16(gwb16 + ((0*4 + grp)*16 + ln15)*8);
        short8 bf1 = ld_frag16(gwb16 + ((1*4 + grp)*16 + ln15)*8);
        float Acoef = gac[ln15];
        float Ccoef = gac[16 + ln15];
        float bpv  = bp[ln15 & 7];
        float bpgv = bpg[ln15 & 7];
        size_t scb = (size_t)bi * (JJ/16) * 128;   // = bi * 8192
        const float* wbase = pe + peRow + (size_t)(wid*256) * PP + r4*64 + q4*4;
        const float* mbase = pmask + (size_t)bi*JJ + wid*256 + r4;
        int selg = grp >> 1;
        int idx0 = 4*ln15 + 2*(grp & 1);

        for (int tile = 0; tile < 16; ++tile){
            const float* pt = wbase + (size_t)tile*1024;
            f4v F0 = ntld4(pt + 0);
            f4v F1 = ntld4(pt + 16);
            f4v F2 = ntld4(pt + 32);
            f4v F3 = ntld4(pt + 48);
            float pmv = mbase[tile*16];
            float s  = (F0.x+F0.y+F0.z+F0.w) + (F1.x+F1.y+F1.z+F1.w)
                     + (F2.x+F2.y+F2.z+F2.w) + (F3.x+F3.y+F3.z+F3.w);
            float sq = F0.x*F0.x+F0.y*F0.y+F0.z*F0.z+F0.w*F0.w
                     + F1.x*F1.x+F1.y*F1.y+F1.z*F1.z+F1.w*F1.w
                     + F2.x*F2.x+F2.y*F2.y+F2.z*F2.z+F2.w*F2.w
                     + F3.x*F3.x+F3.y*F3.y+F3.z*F3.z+F3.w*F3.w;
            s  += __shfl_xor(s, 1);  s  += __shfl_xor(s, 2);
            sq += __shfl_xor(sq, 1); sq += __shfl_xor(sq, 2);
            u32 W00 = pk2(F0.x,F0.y), W01 = pk2(F0.z,F0.w);
            u32 W10 = pk2(F1.x,F1.y), W11 = pk2(F1.z,F1.w);
            u32 W20 = pk2(F2.x,F2.y), W21 = pk2(F2.z,F2.w);
            u32 W30 = pk2(F3.x,F3.y), W31 = pk2(F3.z,F3.w);
            u32 Wa0 = selg ? W10 : W00, Wa1 = selg ? W11 : W01;
            u32 Wb0 = selg ? W30 : W20, Wb1 = selg ? W31 : W21;
            u32 aw[4];
            aw[0] = __shfl(Wa0, idx0);     aw[1] = __shfl(Wa1, idx0);
            aw[2] = __shfl(Wa0, idx0 + 1); aw[3] = __shfl(Wa1, idx0 + 1);
            short8 a0; __builtin_memcpy(&a0, aw, 16);
            aw[0] = __shfl(Wb0, idx0);     aw[1] = __shfl(Wb1, idx0);
            aw[2] = __shfl(Wb0, idx0 + 1); aw[3] = __shfl(Wb1, idx0 + 1);
            short8 a1; __builtin_memcpy(&a1, aw, 16);
            f32x4 acc = MFMA16(a0, bf0, zeroc);
            acc = MFMA16(a1, bf1, acc);        // acc[r] = S[j0+grp*4+r][c=ln15]
            float pbq[4];
            #pragma unroll
            for (int r = 0; r < 4; ++r){
                int sl = 16*grp + 4*r;
                float mean = __shfl(s,  sl) * (1.0f/PP);
                float msq  = __shfl(sq, sl) * (1.0f/PP);
                float rstd = rsqrtf(msq - mean*mean + EPSF);
                float afull = rstd*(acc[r] - mean*Acoef) + Ccoef;
                float other = __shfl_xor(afull, 8);
                float mbv = INFF * (__shfl(pmv, sl) - 1.0f);
                pbq[r] = (afull + bpv) * sigmoidf_(other + bpgv) + mbv;
            }
            if (ln15 < 8){
                int jblk = wid*16 + tile;       // j0 >> 4
                uint2 st;
                st.x = pk2(pbq[0], pbq[1]);
                st.y = pk2(pbq[2], pbq[3]);
                *(uint2*)&sc[scb + (size_t)jblk*128 + ln15*16 + grp*4] = st;
            }
        }
    } else {
        // ---------- proj body: MFMA GEMM, no LDS, no barriers ----------
        int pid = q5;                              // 0..511
        int z = pid & 3, ct = (pid >> 2) & 3, rt = pid >> 4;
        const u16* X16 = (z==1 || z==2) ? nj16 : ni16;
        int row0 = rt*64, c0 = ct*64;
        int rowb = row0 + wid*16;
        const u16* xrow = X16 + (size_t)(rowb + ln15)*DD;
        const u16* wz = wb16 + (size_t)z*16*4*256*8;
        f32x4 acc0 = zeroc, acc1 = zeroc, acc2 = zeroc, acc3 = zeroc;
        for (int ks = 0; ks < 16; ++ks){
            short8 af = ld_frag16(xrow + ks*32 + grp*8);
            const u16* wk2 = wz + ((size_t)(ks*4 + grp)*256)*8;
            short8 b0 = ld_frag16(wk2 + (c0 + 0*16 + ln15)*8);
            short8 b1 = ld_frag16(wk2 + (c0 + 1*16 + ln15)*8);
            short8 b2 = ld_frag16(wk2 + (c0 + 2*16 + ln15)*8);
            short8 b3 = ld_frag16(wk2 + (c0 + 3*16 + ln15)*8);
            acc0 = MFMA16(af, b0, acc0);
            acc1 = MFMA16(af, b1, acc1);
            acc2 = MFMA16(af, b2, acc2);
            acc3 = MFMA16(af, b3, acc3);
        }
        int b = rowb >> 10, ij0 = (rowb & 1023) + grp*4;
        if (z == 2){
            #pragma unroll
            for (int cf = 0; cf < 4; ++cf){
                f32x4 a = (cf==0)?acc0:(cf==1)?acc1:(cf==2)?acc2:acc3;
                int chc = c0 + cf*16 + ln15;
                int h = chc >> 5, c = chc & 31;
                uint2 st;
                st.x = pk2(a[0], a[1]);
                st.y = pk2(a[2], a[3]);
                *(uint2*)&vT[((size_t)(b*HH + h)*CC + c)*JJ + ij0] = st;
            }
        } else if (z == 3){
            float bgv[4];
            #pragma unroll
            for (int cf = 0; cf < 4; ++cf) bgv[cf] = bg[c0 + cf*16 + ln15];
            #pragma unroll
            for (int cf = 0; cf < 4; ++cf){
                f32x4 a = (cf==0)?acc0:(cf==1)?acc1:(cf==2)?acc2:acc3;
                int chc = c0 + cf*16 + ln15;
                #pragma unroll
                for (int r = 0; r < 4; ++r){
                    int row = rowb + grp*4 + r;
                    g[(size_t)row*HC + chc] = sigmoidf_(a[r] + bgv[cf]);
                }
            }
        } else {
            u16* dstb = (z == 0) ? qbf : kbf;
            #pragma unroll
            for (int cf = 0; cf < 4; ++cf){
                f32x4 a = (cf==0)?acc0:(cf==1)?acc1:(cf==2)?acc2:acc3;
                int chc = c0 + cf*16 + ln15;
                int h = chc >> 5, c = chc & 31;
                #pragma unroll
                for (int r = 0; r < 4; ++r){
                    dstb[((size_t)(b*HH + h)*II + ij0 + r)*CC + c] = f2bf(a[r]);
                }
            }
        }
    }
}

// ---------------- K3: fused flash attention (parallel 4-wave epilogue, bf16 o) ----------------
__global__ __launch_bounds__(256) void fattn_kernel(
    const u16* __restrict__ qbf, const u16* __restrict__ kbf,
    const u16* __restrict__ vT, const u16* __restrict__ sc,
    const float* __restrict__ g, u16* __restrict__ o16)
{
    int it = blockIdx.x, h = blockIdx.y, b = blockIdx.z;
    int t = threadIdx.x;
    int w = t >> 6, lane = t & 63;       // jw = w (0..3)
    int ln15 = lane & 15, grp = lane >> 4;
    int i0 = it*16;
    size_t bh = (size_t)(b*HH + h);

    short8 qf = ld_frag16(qbf + (bh*II + i0 + ln15)*CC + grp*8);
    const u16* kbase = kbf + bh*JJ*CC;
    const u16* vbase = vT + bh*CC*JJ;
    // sc layout [i][jblk][h][jw]: per-row base + head offset
    size_t scb = (size_t)(b*II + i0 + ln15) * 8192 + h*16;

    f32x4 oacc0 = {0.f,0.f,0.f,0.f}, oacc1 = {0.f,0.f,0.f,0.f};
    float m = -INFINITY, l = 0.f;
    const f32x4 zeroc = {0.f,0.f,0.f,0.f};

    for (int ch = 0; ch < 8; ++ch){
        int j0 = (ch*4 + w)*32;
        int jb = j0 >> 4;
        short8 ka0 = ld_frag16(kbase + (size_t)(j0 + ln15)*CC + grp*8);
        short8 ka1 = ld_frag16(kbase + (size_t)(j0 + 16 + ln15)*CC + grp*8);
        f32x4 s0 = MFMA16(ka0, qf, zeroc);   // S[j0+grp*4+r][i0+ln15]
        f32x4 s1 = MFMA16(ka1, qf, zeroc);
        uint2 b0 = *(const uint2*)&sc[scb + (size_t)jb*128 + grp*4];
        uint2 b1 = *(const uint2*)&sc[scb + (size_t)(jb+1)*128 + grp*4];
        float s[8];
        s[0] = s0[0] + bf16lo(b0.x); s[1] = s0[1] + bf16hi(b0.x);
        s[2] = s0[2] + bf16lo(b0.y); s[3] = s0[3] + bf16hi(b0.y);
        s[4] = s1[0] + bf16lo(b1.x); s[5] = s1[1] + bf16hi(b1.x);
        s[6] = s1[2] + bf16lo(b1.y); s[7] = s1[3] + bf16hi(b1.y);
        float pm = s[0];
        #pragma unroll
        for (int e = 1; e < 8; ++e) pm = fmaxf(pm, s[e]);
        pm = fmaxf(pm, __shfl_xor(pm, 16));
        pm = fmaxf(pm, __shfl_xor(pm, 32));
        float mn = fmaxf(m, pm);
        float alpha = __expf(m - mn);
        m = mn;
        float p[8], psum = 0.f;
        #pragma unroll
        for (int e = 0; e < 8; ++e){ p[e] = __expf(s[e] - m); psum += p[e]; }
        l = l*alpha + psum;
        #pragma unroll
        for (int r = 0; r < 4; ++r){
            float ar = __shfl(alpha, grp*4 + r);
            oacc0[r] *= ar; oacc1[r] *= ar;
        }
        u32 pw[4];
        pw[0] = pk2(p[0], p[1]); pw[1] = pk2(p[2], p[3]);
        pw[2] = pk2(p[4], p[5]); pw[3] = pk2(p[6], p[7]);
        short8 pa; __builtin_memcpy(&pa, pw, 16);
        const u16* vr0 = vbase + (size_t)(ln15)*JJ + j0 + grp*4;
        const u16* vr1 = vbase + (size_t)(16 + ln15)*JJ + j0 + grp*4;
        uint2 va0 = *(const uint2*)vr0, va1 = *(const uint2*)(vr0 + 16);
        u32 vw[4] = {va0.x, va0.y, va1.x, va1.y};
        short8 vb0; __builtin_memcpy(&vb0, vw, 16);
        uint2 vc0 = *(const uint2*)vr1, vc1 = *(const uint2*)(vr1 + 16);
        u32 vx[4] = {vc0.x, vc0.y, vc1.x, vc1.y};
        short8 vb1; __builtin_memcpy(&vb1, vx, 16);
        oacc0 = MFMA16(pa, vb0, oacc0);
        oacc1 = MFMA16(pa, vb1, oacc1);
    }
    l += __shfl_xor(l, 16); l += __shfl_xor(l, 32);

    __shared__ float mb[4][64], lb[4][64], ob[4][8][64];
    mb[w][lane] = m; lb[w][lane] = l;
    #pragma unroll
    for (int r = 0; r < 4; ++r){ ob[w][r][lane] = oacc0[r]; ob[w][4+r][lane] = oacc1[r]; }
    __syncthreads();
    {
        int r = w;                           // each wave merges one r (4x parallel)
        int row = grp*4 + r;                 // 0..15
        float M = fmaxf(fmaxf(mb[0][row], mb[1][row]), fmaxf(mb[2][row], mb[3][row]));
        float sw[4], L = 0.f;
        #pragma unroll
        for (int w2 = 0; w2 < 4; ++w2){
            sw[w2] = __expf(mb[w2][row] - M);
            L += lb[w2][row] * sw[w2];
        }
        float inv = 1.0f / L;
        float o0 = 0.f, o1 = 0.f;
        #pragma unroll
        for (int w2 = 0; w2 < 4; ++w2){
            o0 += ob[w2][r][lane]   * sw[w2];
            o1 += ob[w2][4+r][lane] * sw[w2];
        }
        size_t rb = (size_t)(b*II + i0 + row)*HC + h*CC;
        o16[rb + ln15]      = f2bf(o0 * inv * g[rb + ln15]);
        o16[rb + 16 + ln15] = f2bf(o1 * inv * g[rb + 16 + ln15]);
    }
}

// ---------------- K4: out = ni + (o16 @ Wo + bo) * mask  (MFMA, LDS-free) ----------------
__global__ __launch_bounds__(256) void out_mfma(
    const u16* __restrict__ o16, const u16* __restrict__ wo16,
    const float* __restrict__ bo, const float* __restrict__ ni,
    const float* __restrict__ nmask, float* __restrict__ out)
{
    int rt = blockIdx.x, ct = blockIdx.y;      // 32 x 8
    int t = threadIdx.x;
    int wid = t >> 6, lane = t & 63;
    int ln15 = lane & 15, grp = lane >> 4;
    const f32x4 zeroc = {0.f,0.f,0.f,0.f};
    int rowb = rt*64 + wid*16, c0 = ct*64;
    const u16* xrow = o16 + (size_t)(rowb + ln15)*HC;
    f32x4 acc0 = zeroc, acc1 = zeroc, acc2 = zeroc, acc3 = zeroc;
    for (int ks = 0; ks < 8; ++ks){
        short8 af = ld_frag16(xrow + ks*32 + grp*8);
        const u16* wk2 = wo16 + ((size_t)(ks*4 + grp)*DD)*8;
        short8 b0 = ld_frag16(wk2 + (c0 + 0*16 + ln15)*8);
        short8 b1 = ld_frag16(wk2 + (c0 + 1*16 + ln15)*8);
        short8 b2 = ld_frag16(wk2 + (c0 + 2*16 + ln15)*8);
        short8 b3 = ld_frag16(wk2 + (c0 + 3*16 + ln15)*8);
        acc0 = MFMA16(af, b0, acc0);
        acc1 = MFMA16(af, b1, acc1);
        acc2 = MFMA16(af, b2, acc2);
        acc3 = MFMA16(af, b3, acc3);
    }
    float msk[4], niv;
    #pragma unroll
    for (int r = 0; r < 4; ++r) msk[r] = nmask[rowb + grp*4 + r];
    #pragma unroll
    for (int cf = 0; cf < 4; ++cf){
        f32x4 a = (cf==0)?acc0:(cf==1)?acc1:(cf==2)?acc2:acc3;
        int chc = c0 + cf*16 + ln15;
        float bov = bo[chc];
        #pragma unroll
        for (int r = 0; r < 4; ++r){
            int row = rowb + grp*4 + r;
            niv = ni[(size_t)row*DD + chc];
            out[(size_t)row*DD + chc] = (a[r] + bov)*msk[r] + niv;
        }
    }
}

extern "C" void kernel_launch(void* const* d_in, const int* in_sizes, int n_in,
                              void* d_out, int out_size, void* d_ws, size_t ws_size,
                              hipStream_t stream)
{
    const float* node_i = (const float*)d_in[0];
    const float* node_j = (const float*)d_in[1];
    const float* pe     = (const float*)d_in[2];
    const float* pmask  = (const float*)d_in[3];
    const float* nmask  = (const float*)d_in[4];
    const float* ln_i_g = (const float*)d_in[5];
    const float* ln_i_b = (const float*)d_in[6];
    const float* ln_j_g = (const float*)d_in[7];
    const float* ln_j_b = (const float*)d_in[8];
    const float* ln_p_g = (const float*)d_in[9];
    const float* ln_p_b = (const float*)d_in[10];
    const float* Wp     = (const float*)d_in[11];
    const float* bp     = (const float*)d_in[12];
    const float* Wpg    = (const float*)d_in[13];
    const float* bpg    = (const float*)d_in[14];
    const float* Wq     = (const float*)d_in[15];
    const float* Wk     = (const float*)d_in[16];
    const float* Wv     = (const float*)d_in[17];
    const float* Wg     = (const float*)d_in[18];
    const float* bg     = (const float*)d_in[19];
    const float* Wo     = (const float*)d_in[20];
    const float* bo     = (const float*)d_in[21];
    float* out = (float*)d_out;

    char* ws = (char*)d_ws;
    float* ni    = (float*)(ws + 0);                     // 4 MB  (f32, residual)
    u16*   ni16  = (u16*)  (ws + ((size_t)4<<20));       // 2 MB
    u16*   nj16  = (u16*)  (ws + ((size_t)6<<20));       // 2 MB
    u16*   qbf   = (u16*)  (ws + ((size_t)8<<20));       // 1 MB
    u16*   kbf   = (u16*)  (ws + ((size_t)9<<20));       // 1 MB
    u16*   vTb   = (u16*)  (ws + ((size_t)10<<20));      // 1 MB
    u16*   gwb16 = (u16*)  (ws + ((size_t)11<<20));      // 2 KB
    float* gac   = (float*)(ws + ((size_t)11<<20) + 4096); // 128 B
    u16*   wb16  = (u16*)  (ws + ((size_t)12<<20));      // 1 MB
    u16*   wo16  = (u16*)  (ws + ((size_t)13<<20));      // 256 KB
    float* g     = (float*)(ws + ((size_t)14<<20));      // 2 MB
    u16*   o16   = (u16*)  (ws + ((size_t)16<<20));      // 1 MB
    u16*   sc    = (u16*)  (ws + ((size_t)18<<20));      // 32 MB

    ln_kernel<<<dim3(4737), dim3(128), 0, stream>>>(
        node_i, node_j, ln_i_g, ln_i_b, ln_j_g, ln_j_b,
        ln_p_g, ln_p_b, Wp, Wpg, Wq, Wk, Wv, Wg, Wo,
        ni, ni16, nj16, gwb16, gac, wb16, wo16);
    combo_kernel<<<dim3(2560), dim3(256), 0, stream>>>(
        pe, pmask, gwb16, gac, bp, bpg, sc,
        ni16, nj16, wb16, bg, qbf, kbf, vTb, g);
    fattn_kernel<<<dim3(64,8,2), dim3(256), 0, stream>>>(qbf, kbf, vTb, sc, g, o16);
    out_mfma<<<dim3(32,8), dim3(256), 0, stream>>>(o16, wo16, bo, ni, nmask, out);
}

// Round 22
// 164.970 us; speedup vs baseline: 1.1162x; 1.0728x over previous
//
#include <hip/hip_runtime.h>
#include <hip/hip_bf16.h>

#define BB 2
#define II 1024
#define JJ 1024
#define DD 512
#define PP 64
#define HH 8
#define CC 32
#define HC 256
#define INFF 1.0e9f
#define EPSF 1e-5f

typedef unsigned int u32;
typedef unsigned short u16;
typedef __attribute__((ext_vector_type(8))) short short8;
typedef __attribute__((ext_vector_type(4))) float f32x4;
typedef __attribute__((ext_vector_type(4))) float f4v;

#define MFMA16(a,b,c) __builtin_amdgcn_mfma_f32_16x16x32_bf16(a,b,c,0,0,0)

__device__ inline float bf16lo(u32 u){ u32 x = u << 16; float f; __builtin_memcpy(&f,&x,4); return f; }
__device__ inline float bf16hi(u32 u){ u32 x = u & 0xFFFF0000u; float f; __builtin_memcpy(&f,&x,4); return f; }
__device__ inline float bf16s(u16 h){ u32 x = ((u32)h) << 16; float f; __builtin_memcpy(&f,&x,4); return f; }
__device__ inline u32 pk2(float a, float b){
    __hip_bfloat162 h2 = __float22bfloat162_rn(float2{a, b});
    u32 r; __builtin_memcpy(&r, &h2, 4); return r;
}
__device__ inline u16 f2bf(float f){
    __hip_bfloat16 h = __float2bfloat16(f);
    u16 r; __builtin_memcpy(&r, &h, 2); return r;
}
__device__ inline float sigmoidf_(float x){ return 1.0f/(1.0f + __expf(-x)); }
__device__ inline short8 ld_frag16(const u16* p){ short8 v; __builtin_memcpy(&v, p, 16); return v; }
__device__ inline f4v ntld4(const float* p){ return __builtin_nontemporal_load((const f4v*)p); }

// ---------------- K1: LayerNorm + prep (gwb16/gac, wb16, wo16) ----------------
__global__ __launch_bounds__(128) void ln_kernel(
    const float* __restrict__ xi, const float* __restrict__ xj,
    const float* __restrict__ gi, const float* __restrict__ bi,
    const float* __restrict__ gj, const float* __restrict__ bj,
    const float* __restrict__ lng, const float* __restrict__ lnb,
    const float* __restrict__ Wp, const float* __restrict__ Wpg,
    const float* __restrict__ Wq, const float* __restrict__ Wk,
    const float* __restrict__ Wv, const float* __restrict__ Wg,
    const float* __restrict__ Wo,
    float* __restrict__ ni, u16* __restrict__ ni16, u16* __restrict__ nj16,
    u16* __restrict__ gwb16, float* __restrict__ gac,
    u16* __restrict__ wb16, u16* __restrict__ wo16)
{
    const float qscale = 0.17677669529663687f;   // 1/sqrt(32)
    if (blockIdx.x == 4096){
        int t = threadIdx.x;
        #pragma unroll
        for (int e = 0; e < 8; ++e){
            int idx = t*8 + e;              // 0..1023
            int ee = idx & 7, nn = (idx >> 3) & 15, gg = (idx >> 7) & 3, ch = (idx >> 9) & 1;
            int k = ch*32 + gg*8 + ee;
            float wv = lng[k] * ((nn < 8) ? Wp[k*8 + nn] : Wpg[k*8 + (nn-8)]);
            gwb16[idx] = f2bf(wv);
        }
        if (t < 32){
            int c = t & 15;
            float acc2 = 0.f;
            for (int p = 0; p < 64; ++p){
                float wv = (c < 8) ? Wp[p*8+c] : Wpg[p*8+(c-8)];
                acc2 += wv * ((t < 16) ? lng[p] : lnb[p]);
            }
            gac[t] = acc2;                  // [0..15]=A, [16..31]=C
        }
        return;
    }
    if (blockIdx.x >= 4609){
        // Wo conversion -> B-frag layout wo16[((ks*4+grp)*512 + n)*8 + e], k = ks*32+grp*8+e
        int wb = blockIdx.x - 4609;         // 0..127
        int t = threadIdx.x;
        int idx0 = wb*1024 + t*8;
        int n = (idx0 >> 3) & 511, grp = (idx0 >> 12) & 3, ks = idx0 >> 14;
        int kb = ks*32 + grp*8;
        u16 outv[8];
        #pragma unroll
        for (int e = 0; e < 8; ++e)
            outv[e] = f2bf(Wo[(size_t)(kb + e)*DD + n]);
        *(uint4*)&wo16[idx0] = *(uint4*)outv;
        return;
    }
    if (blockIdx.x > 4096){
        // W{q,k,v,g} conversion -> wb16[(((z*16+ks)*4+grp)*256 + n)*8 + e]
        int wb = blockIdx.x - 4097;         // 0..511
        int t = threadIdx.x;
        int idx0 = wb*1024 + t*8;
        int n = (idx0 >> 3) & 255, grp = (idx0 >> 11) & 3;
        int ks = (idx0 >> 13) & 15, z = idx0 >> 17;
        const float* Wsrc = (z==0)?Wq : (z==1)?Wk : (z==2)?Wv : Wg;
        int kbase2 = ks*32 + grp*8;
        u16 outv[8];
        #pragma unroll
        for (int e = 0; e < 8; ++e){
            float wv = Wsrc[(size_t)(kbase2 + e)*HC + n];
            if (z == 0) wv *= qscale;
            outv[e] = f2bf(wv);
        }
        *(uint4*)&wb16[idx0] = *(uint4*)outv;
        return;
    }
    int row = blockIdx.x;           // 0..4095
    int side = row >> 11;
    int r = row & 2047;
    const float* x = (side ? xj : xi) + (size_t)r * DD;
    const float* gg = side ? gj : gi;
    const float* bbp = side ? bj : bi;
    int t = threadIdx.x;
    float4 v = ((const float4*)x)[t];
    float s  = v.x + v.y + v.z + v.w;
    float sq = v.x*v.x + v.y*v.y + v.z*v.z + v.w*v.w;
    #pragma unroll
    for (int off = 32; off; off >>= 1){ s += __shfl_down(s, off); sq += __shfl_down(sq, off); }
    __shared__ float ls[2], lq[2];
    int w = t >> 6, lane = t & 63;
    if (lane == 0){ ls[w] = s; lq[w] = sq; }
    __syncthreads();
    s = ls[0] + ls[1]; sq = lq[0] + lq[1];
    float mean = s * (1.0f/DD);
    float var  = sq * (1.0f/DD) - mean*mean;
    float rstd = rsqrtf(var + EPSF);
    float4 gv = ((const float4*)gg)[t];
    float4 bv = ((const float4*)bbp)[t];
    float4 o;
    o.x = (v.x-mean)*rstd*gv.x + bv.x;
    o.y = (v.y-mean)*rstd*gv.y + bv.y;
    o.z = (v.z-mean)*rstd*gv.z + bv.z;
    o.w = (v.w-mean)*rstd*gv.w + bv.w;
    if (!side) ((float4*)(ni + (size_t)r*DD))[t] = o;
    u16* x16 = (side ? nj16 : ni16) + (size_t)r*DD;
    uint2 pk; pk.x = pk2(o.x, o.y); pk.y = pk2(o.z, o.w);
    *(uint2*)&x16[t*4] = pk;
}

// ---------------- K2: combo — bias (half-rows, MFMA stream, NT loads, coalesced sc) + proj ----------------
// sc layout: [bi][jblk = j/16][h][j%16]
// grid 4608: n%9==8 -> proj (512), else bias half-row (4096): bi = id>>1, half = id&1
__global__ __launch_bounds__(256) void combo_kernel(
    const float* __restrict__ pe, const float* __restrict__ pmask,
    const u16* __restrict__ gwb16, const float* __restrict__ gac,
    const float* __restrict__ bp, const float* __restrict__ bpg,
    u16* __restrict__ sc,
    const u16* __restrict__ ni16, const u16* __restrict__ nj16,
    const u16* __restrict__ wb16, const float* __restrict__ bg,
    u16* __restrict__ qbf, u16* __restrict__ kbf,
    u16* __restrict__ vT, float* __restrict__ g)
{
    int n = blockIdx.x;
    int q9 = n / 9, r9 = n - q9*9;
    int t = threadIdx.x;
    int wid = t >> 6, lane = t & 63;
    int ln15 = lane & 15, grp = lane >> 4;
    const f32x4 zeroc = {0.f,0.f,0.f,0.f};

    if (r9 != 8){
        // ---------- bias body: 512 j's per block ----------
        int id = n - q9;                           // 0..4095
        int bi = id >> 1, half = id & 1;
        const size_t peRow = (size_t)bi * JJ * PP;
        int r4 = lane >> 2, q4 = lane & 3;
        int jbase = half*512 + wid*128;            // this wave's 128 j's
        short8 bf0 = ld_frag16(gwb16 + ((0*4 + grp)*16 + ln15)*8);
        short8 bf1 = ld_frag16(gwb16 + ((1*4 + grp)*16 + ln15)*8);
        float Acoef = gac[ln15];
        float Ccoef = gac[16 + ln15];
        float bpv  = bp[ln15 & 7];
        float bpgv = bpg[ln15 & 7];
        size_t scb = (size_t)bi * 8192;            // bi * (JJ/16) * 128
        const float* wbase = pe + peRow + (size_t)jbase * PP + r4*64 + q4*4;
        const float* mbase = pmask + (size_t)bi*JJ + jbase + r4;
        int selg = grp >> 1;
        int idx0 = 4*ln15 + 2*(grp & 1);

        for (int tile = 0; tile < 8; ++tile){
            const float* pt = wbase + (size_t)tile*1024;
            f4v F0 = ntld4(pt + 0);
            f4v F1 = ntld4(pt + 16);
            f4v F2 = ntld4(pt + 32);
            f4v F3 = ntld4(pt + 48);
            float pmv = mbase[tile*16];
            float s  = (F0.x+F0.y+F0.z+F0.w) + (F1.x+F1.y+F1.z+F1.w)
                     + (F2.x+F2.y+F2.z+F2.w) + (F3.x+F3.y+F3.z+F3.w);
            float sq = F0.x*F0.x+F0.y*F0.y+F0.z*F0.z+F0.w*F0.w
                     + F1.x*F1.x+F1.y*F1.y+F1.z*F1.z+F1.w*F1.w
                     + F2.x*F2.x+F2.y*F2.y+F2.z*F2.z+F2.w*F2.w
                     + F3.x*F3.x+F3.y*F3.y+F3.z*F3.z+F3.w*F3.w;
            s  += __shfl_xor(s, 1);  s  += __shfl_xor(s, 2);
            sq += __shfl_xor(sq, 1); sq += __shfl_xor(sq, 2);
            u32 W00 = pk2(F0.x,F0.y), W01 = pk2(F0.z,F0.w);
            u32 W10 = pk2(F1.x,F1.y), W11 = pk2(F1.z,F1.w);
            u32 W20 = pk2(F2.x,F2.y), W21 = pk2(F2.z,F2.w);
            u32 W30 = pk2(F3.x,F3.y), W31 = pk2(F3.z,F3.w);
            u32 Wa0 = selg ? W10 : W00, Wa1 = selg ? W11 : W01;
            u32 Wb0 = selg ? W30 : W20, Wb1 = selg ? W31 : W21;
            u32 aw[4];
            aw[0] = __shfl(Wa0, idx0);     aw[1] = __shfl(Wa1, idx0);
            aw[2] = __shfl(Wa0, idx0 + 1); aw[3] = __shfl(Wa1, idx0 + 1);
            short8 a0; __builtin_memcpy(&a0, aw, 16);
            aw[0] = __shfl(Wb0, idx0);     aw[1] = __shfl(Wb1, idx0);
            aw[2] = __shfl(Wb0, idx0 + 1); aw[3] = __shfl(Wb1, idx0 + 1);
            short8 a1; __builtin_memcpy(&a1, aw, 16);
            f32x4 acc = MFMA16(a0, bf0, zeroc);
            acc = MFMA16(a1, bf1, acc);        // acc[r] = S[jbase+tile*16+grp*4+r][c=ln15]
            float pbq[4];
            #pragma unroll
            for (int r = 0; r < 4; ++r){
                int sl = 16*grp + 4*r;
                float mean = __shfl(s,  sl) * (1.0f/PP);
                float msq  = __shfl(sq, sl) * (1.0f/PP);
                float rstd = rsqrtf(msq - mean*mean + EPSF);
                float afull = rstd*(acc[r] - mean*Acoef) + Ccoef;
                float other = __shfl_xor(afull, 8);
                float mbv = INFF * (__shfl(pmv, sl) - 1.0f);
                pbq[r] = (afull + bpv) * sigmoidf_(other + bpgv) + mbv;
            }
            if (ln15 < 8){
                int jblk = (jbase >> 4) + tile;
                uint2 st;
                st.x = pk2(pbq[0], pbq[1]);
                st.y = pk2(pbq[2], pbq[3]);
                *(uint2*)&sc[scb + (size_t)jblk*128 + ln15*16 + grp*4] = st;
            }
        }
    } else {
        // ---------- proj body: MFMA GEMM, no LDS, no barriers ----------
        int pid = q9;                              // 0..511
        int z = pid & 3, ct = (pid >> 2) & 3, rt = pid >> 4;
        const u16* X16 = (z==1 || z==2) ? nj16 : ni16;
        int row0 = rt*64, c0 = ct*64;
        int rowb = row0 + wid*16;
        const u16* xrow = X16 + (size_t)(rowb + ln15)*DD;
        const u16* wz = wb16 + (size_t)z*16*4*256*8;
        f32x4 acc0 = zeroc, acc1 = zeroc, acc2 = zeroc, acc3 = zeroc;
        for (int ks = 0; ks < 16; ++ks){
            short8 af = ld_frag16(xrow + ks*32 + grp*8);
            const u16* wk2 = wz + ((size_t)(ks*4 + grp)*256)*8;
            short8 b0 = ld_frag16(wk2 + (c0 + 0*16 + ln15)*8);
            short8 b1 = ld_frag16(wk2 + (c0 + 1*16 + ln15)*8);
            short8 b2 = ld_frag16(wk2 + (c0 + 2*16 + ln15)*8);
            short8 b3 = ld_frag16(wk2 + (c0 + 3*16 + ln15)*8);
            acc0 = MFMA16(af, b0, acc0);
            acc1 = MFMA16(af, b1, acc1);
            acc2 = MFMA16(af, b2, acc2);
            acc3 = MFMA16(af, b3, acc3);
        }
        int b = rowb >> 10, ij0 = (rowb & 1023) + grp*4;
        if (z == 2){
            #pragma unroll
            for (int cf = 0; cf < 4; ++cf){
                f32x4 a = (cf==0)?acc0:(cf==1)?acc1:(cf==2)?acc2:acc3;
                int chc = c0 + cf*16 + ln15;
                int h = chc >> 5, c = chc & 31;
                uint2 st;
                st.x = pk2(a[0], a[1]);
                st.y = pk2(a[2], a[3]);
                *(uint2*)&vT[((size_t)(b*HH + h)*CC + c)*JJ + ij0] = st;
            }
        } else if (z == 3){
            float bgv[4];
            #pragma unroll
            for (int cf = 0; cf < 4; ++cf) bgv[cf] = bg[c0 + cf*16 + ln15];
            #pragma unroll
            for (int cf = 0; cf < 4; ++cf){
                f32x4 a = (cf==0)?acc0:(cf==1)?acc1:(cf==2)?acc2:acc3;
                int chc = c0 + cf*16 + ln15;
                #pragma unroll
                for (int r = 0; r < 4; ++r){
                    int row = rowb + grp*4 + r;
                    g[(size_t)row*HC + chc] = sigmoidf_(a[r] + bgv[cf]);
                }
            }
        } else {
            u16* dstb = (z == 0) ? qbf : kbf;
            #pragma unroll
            for (int cf = 0; cf < 4; ++cf){
                f32x4 a = (cf==0)?acc0:(cf==1)?acc1:(cf==2)?acc2:acc3;
                int chc = c0 + cf*16 + ln15;
                int h = chc >> 5, c = chc & 31;
                #pragma unroll
                for (int r = 0; r < 4; ++r){
                    dstb[((size_t)(b*HH + h)*II + ij0 + r)*CC + c] = f2bf(a[r]);
                }
            }
        }
    }
}

// ---------------- K3: fused flash attention (parallel 4-wave epilogue, bf16 o) ----------------
__global__ __launch_bounds__(256) void fattn_kernel(
    const u16* __restrict__ qbf, const u16* __restrict__ kbf,
    const u16* __restrict__ vT, const u16* __restrict__ sc,
    const float* __restrict__ g, u16* __restrict__ o16)
{
    int it = blockIdx.x, h = blockIdx.y, b = blockIdx.z;
    int t = threadIdx.x;
    int w = t >> 6, lane = t & 63;       // jw = w (0..3)
    int ln15 = lane & 15, grp = lane >> 4;
    int i0 = it*16;
    size_t bh = (size_t)(b*HH + h);

    short8 qf = ld_frag16(qbf + (bh*II + i0 + ln15)*CC + grp*8);
    const u16* kbase = kbf + bh*JJ*CC;
    const u16* vbase = vT + bh*CC*JJ;
    // sc layout [i][jblk][h][jw]: per-row base + head offset
    size_t scb = (size_t)(b*II + i0 + ln15) * 8192 + h*16;

    f32x4 oacc0 = {0.f,0.f,0.f,0.f}, oacc1 = {0.f,0.f,0.f,0.f};
    float m = -INFINITY, l = 0.f;
    const f32x4 zeroc = {0.f,0.f,0.f,0.f};

    for (int ch = 0; ch < 8; ++ch){
        int j0 = (ch*4 + w)*32;
        int jb = j0 >> 4;
        short8 ka0 = ld_frag16(kbase + (size_t)(j0 + ln15)*CC + grp*8);
        short8 ka1 = ld_frag16(kbase + (size_t)(j0 + 16 + ln15)*CC + grp*8);
        f32x4 s0 = MFMA16(ka0, qf, zeroc);   // S[j0+grp*4+r][i0+ln15]
        f32x4 s1 = MFMA16(ka1, qf, zeroc);
        uint2 b0 = *(const uint2*)&sc[scb + (size_t)jb*128 + grp*4];
        uint2 b1 = *(const uint2*)&sc[scb + (size_t)(jb+1)*128 + grp*4];
        float s[8];
        s[0] = s0[0] + bf16lo(b0.x); s[1] = s0[1] + bf16hi(b0.x);
        s[2] = s0[2] + bf16lo(b0.y); s[3] = s0[3] + bf16hi(b0.y);
        s[4] = s1[0] + bf16lo(b1.x); s[5] = s1[1] + bf16hi(b1.x);
        s[6] = s1[2] + bf16lo(b1.y); s[7] = s1[3] + bf16hi(b1.y);
        float pm = s[0];
        #pragma unroll
        for (int e = 1; e < 8; ++e) pm = fmaxf(pm, s[e]);
        pm = fmaxf(pm, __shfl_xor(pm, 16));
        pm = fmaxf(pm, __shfl_xor(pm, 32));
        float mn = fmaxf(m, pm);
        float alpha = __expf(m - mn);
        m = mn;
        float p[8], psum = 0.f;
        #pragma unroll
        for (int e = 0; e < 8; ++e){ p[e] = __expf(s[e] - m); psum += p[e]; }
        l = l*alpha + psum;
        #pragma unroll
        for (int r = 0; r < 4; ++r){
            float ar = __shfl(alpha, grp*4 + r);
            oacc0[r] *= ar; oacc1[r] *= ar;
        }
        u32 pw[4];
        pw[0] = pk2(p[0], p[1]); pw[1] = pk2(p[2], p[3]);
        pw[2] = pk2(p[4], p[5]); pw[3] = pk2(p[6], p[7]);
        short8 pa; __builtin_memcpy(&pa, pw, 16);
        const u16* vr0 = vbase + (size_t)(ln15)*JJ + j0 + grp*4;
        const u16* vr1 = vbase + (size_t)(16 + ln15)*JJ + j0 + grp*4;
        uint2 va0 = *(const uint2*)vr0, va1 = *(const uint2*)(vr0 + 16);
        u32 vw[4] = {va0.x, va0.y, va1.x, va1.y};
        short8 vb0; __builtin_memcpy(&vb0, vw, 16);
        uint2 vc0 = *(const uint2*)vr1, vc1 = *(const uint2*)(vr1 + 16);
        u32 vx[4] = {vc0.x, vc0.y, vc1.x, vc1.y};
        short8 vb1; __builtin_memcpy(&vb1, vx, 16);
        oacc0 = MFMA16(pa, vb0, oacc0);
        oacc1 = MFMA16(pa, vb1, oacc1);
    }
    l += __shfl_xor(l, 16); l += __shfl_xor(l, 32);

    __shared__ float mb[4][64], lb[4][64], ob[4][8][64];
    mb[w][lane] = m; lb[w][lane] = l;
    #pragma unroll
    for (int r = 0; r < 4; ++r){ ob[w][r][lane] = oacc0[r]; ob[w][4+r][lane] = oacc1[r]; }
    __syncthreads();
    {
        int r = w;                           // each wave merges one r (4x parallel)
        int row = grp*4 + r;                 // 0..15
        float M = fmaxf(fmaxf(mb[0][row], mb[1][row]), fmaxf(mb[2][row], mb[3][row]));
        float sw[4], L = 0.f;
        #pragma unroll
        for (int w2 = 0; w2 < 4; ++w2){
            sw[w2] = __expf(mb[w2][row] - M);
            L += lb[w2][row] * sw[w2];
        }
        float inv = 1.0f / L;
        float o0 = 0.f, o1 = 0.f;
        #pragma unroll
        for (int w2 = 0; w2 < 4; ++w2){
            o0 += ob[w2][r][lane]   * sw[w2];
            o1 += ob[w2][4+r][lane] * sw[w2];
        }
        size_t rb = (size_t)(b*II + i0 + row)*HC + h*CC;
        o16[rb + ln15]      = f2bf(o0 * inv * g[rb + ln15]);
        o16[rb + 16 + ln15] = f2bf(o1 * inv * g[rb + 16 + ln15]);
    }
}

// ---------------- K4: out = ni + (o16 @ Wo + bo) * mask  (MFMA, LDS-free) ----------------
__global__ __launch_bounds__(256) void out_mfma(
    const u16* __restrict__ o16, const u16* __restrict__ wo16,
    const float* __restrict__ bo, const float* __restrict__ ni,
    const float* __restrict__ nmask, float* __restrict__ out)
{
    int rt = blockIdx.x, ct = blockIdx.y;      // 32 x 8
    int t = threadIdx.x;
    int wid = t >> 6, lane = t & 63;
    int ln15 = lane & 15, grp = lane >> 4;
    const f32x4 zeroc = {0.f,0.f,0.f,0.f};
    int rowb = rt*64 + wid*16, c0 = ct*64;
    const u16* xrow = o16 + (size_t)(rowb + ln15)*HC;
    f32x4 acc0 = zeroc, acc1 = zeroc, acc2 = zeroc, acc3 = zeroc;
    for (int ks = 0; ks < 8; ++ks){
        short8 af = ld_frag16(xrow + ks*32 + grp*8);
        const u16* wk2 = wo16 + ((size_t)(ks*4 + grp)*DD)*8;
        short8 b0 = ld_frag16(wk2 + (c0 + 0*16 + ln15)*8);
        short8 b1 = ld_frag16(wk2 + (c0 + 1*16 + ln15)*8);
        short8 b2 = ld_frag16(wk2 + (c0 + 2*16 + ln15)*8);
        short8 b3 = ld_frag16(wk2 + (c0 + 3*16 + ln15)*8);
        acc0 = MFMA16(af, b0, acc0);
        acc1 = MFMA16(af, b1, acc1);
        acc2 = MFMA16(af, b2, acc2);
        acc3 = MFMA16(af, b3, acc3);
    }
    float msk[4], niv;
    #pragma unroll
    for (int r = 0; r < 4; ++r) msk[r] = nmask[rowb + grp*4 + r];
    #pragma unroll
    for (int cf = 0; cf < 4; ++cf){
        f32x4 a = (cf==0)?acc0:(cf==1)?acc1:(cf==2)?acc2:acc3;
        int chc = c0 + cf*16 + ln15;
        float bov = bo[chc];
        #pragma unroll
        for (int r = 0; r < 4; ++r){
            int row = rowb + grp*4 + r;
            niv = ni[(size_t)row*DD + chc];
            out[(size_t)row*DD + chc] = (a[r] + bov)*msk[r] + niv;
        }
    }
}

extern "C" void kernel_launch(void* const* d_in, const int* in_sizes, int n_in,
                              void* d_out, int out_size, void* d_ws, size_t ws_size,
                              hipStream_t stream)
{
    const float* node_i = (const float*)d_in[0];
    const float* node_j = (const float*)d_in[1];
    const float* pe     = (const float*)d_in[2];
    const float* pmask  = (const float*)d_in[3];
    const float* nmask  = (const float*)d_in[4];
    const float* ln_i_g = (const float*)d_in[5];
    const float* ln_i_b = (const float*)d_in[6];
    const float* ln_j_g = (const float*)d_in[7];
    const float* ln_j_b = (const float*)d_in[8];
    const float* ln_p_g = (const float*)d_in[9];
    const float* ln_p_b = (const float*)d_in[10];
    const float* Wp     = (const float*)d_in[11];
    const float* bp     = (const float*)d_in[12];
    const float* Wpg    = (const float*)d_in[13];
    const float* bpg    = (const float*)d_in[14];
    const float* Wq     = (const float*)d_in[15];
    const float* Wk     = (const float*)d_in[16];
    const float* Wv     = (const float*)d_in[17];
    const float* Wg     = (const float*)d_in[18];
    const float* bg     = (const float*)d_in[19];
    const float* Wo     = (const float*)d_in[20];
    const float* bo     = (const float*)d_in[21];
    float* out = (float*)d_out;

    char* ws = (char*)d_ws;
    float* ni    = (float*)(ws + 0);                     // 4 MB  (f32, residual)
    u16*   ni16  = (u16*)  (ws + ((size_t)4<<20));       // 2 MB
    u16*   nj16  = (u16*)  (ws + ((size_t)6<<20));       // 2 MB
    u16*   qbf   = (u16*)  (ws + ((size_t)8<<20));       // 1 MB
    u16*   kbf   = (u16*)  (ws + ((size_t)9<<20));       // 1 MB
    u16*   vTb   = (u16*)  (ws + ((size_t)10<<20));      // 1 MB
    u16*   gwb16 = (u16*)  (ws + ((size_t)11<<20));      // 2 KB
    float* gac   = (float*)(ws + ((size_t)11<<20) + 4096); // 128 B
    u16*   wb16  = (u16*)  (ws + ((size_t)12<<20));      // 1 MB
    u16*   wo16  = (u16*)  (ws + ((size_t)13<<20));      // 256 KB
    float* g     = (float*)(ws + ((size_t)14<<20));      // 2 MB
    u16*   o16   = (u16*)  (ws + ((size_t)16<<20));      // 1 MB
    u16*   sc    = (u16*)  (ws + ((size_t)18<<20));      // 32 MB

    ln_kernel<<<dim3(4737), dim3(128), 0, stream>>>(
        node_i, node_j, ln_i_g, ln_i_b, ln_j_g, ln_j_b,
        ln_p_g, ln_p_b, Wp, Wpg, Wq, Wk, Wv, Wg, Wo,
        ni, ni16, nj16, gwb16, gac, wb16, wo16);
    combo_kernel<<<dim3(4608), dim3(256), 0, stream>>>(
        pe, pmask, gwb16, gac, bp, bpg, sc,
        ni16, nj16, wb16, bg, qbf, kbf, vTb, g);
    fattn_kernel<<<dim3(64,8,2), dim3(256), 0, stream>>>(qbf, kbf, vTb, sc, g, o16);
    out_mfma<<<dim3(32,8), dim3(256), 0, stream>>>(o16, wo16, bo, ni, nmask, out);
}

// Round 23
// 160.173 us; speedup vs baseline: 1.1496x; 1.0300x over previous
//
#include <hip/hip_runtime.h>
#include <hip/hip_bf16.h>

#define BB 2
#define II 1024
#define JJ 1024
#define DD 512
#define PP 64
#define HH 8
#define CC 32
#define HC 256
#define INFF 1.0e9f
#define EPSF 1e-5f

typedef unsigned int u32;
typedef unsigned short u16;
typedef __attribute__((ext_vector_type(8))) short short8;
typedef __attribute__((ext_vector_type(4))) float f32x4;
typedef __attribute__((ext_vector_type(4))) float f4v;

#define MFMA16(a,b,c) __builtin_amdgcn_mfma_f32_16x16x32_bf16(a,b,c,0,0,0)

__device__ inline float bf16lo(u32 u){ u32 x = u << 16; float f; __builtin_memcpy(&f,&x,4); return f; }
__device__ inline float bf16hi(u32 u){ u32 x = u & 0xFFFF0000u; float f; __builtin_memcpy(&f,&x,4); return f; }
__device__ inline float bf16s(u16 h){ u32 x = ((u32)h) << 16; float f; __builtin_memcpy(&f,&x,4); return f; }
__device__ inline u32 pk2(float a, float b){
    __hip_bfloat162 h2 = __float22bfloat162_rn(float2{a, b});
    u32 r; __builtin_memcpy(&r, &h2, 4); return r;
}
__device__ inline u16 f2bf(float f){
    __hip_bfloat16 h = __float2bfloat16(f);
    u16 r; __builtin_memcpy(&r, &h, 2); return r;
}
__device__ inline float sigmoidf_(float x){ return 1.0f/(1.0f + __expf(-x)); }
__device__ inline short8 ld_frag16(const u16* p){ short8 v; __builtin_memcpy(&v, p, 16); return v; }
__device__ inline f4v ntld4(const float* p){ return __builtin_nontemporal_load((const f4v*)p); }

// ---------------- K1: LayerNorm + prep (gwb16/gac, wb16, wo16) ----------------
__global__ __launch_bounds__(128) void ln_kernel(
    const float* __restrict__ xi, const float* __restrict__ xj,
    const float* __restrict__ gi, const float* __restrict__ bi,
    const float* __restrict__ gj, const float* __restrict__ bj,
    const float* __restrict__ lng, const float* __restrict__ lnb,
    const float* __restrict__ Wp, const float* __restrict__ Wpg,
    const float* __restrict__ Wq, const float* __restrict__ Wk,
    const float* __restrict__ Wv, const float* __restrict__ Wg,
    const float* __restrict__ Wo,
    float* __restrict__ ni, u16* __restrict__ ni16, u16* __restrict__ nj16,
    u16* __restrict__ gwb16, float* __restrict__ gac,
    u16* __restrict__ wb16, u16* __restrict__ wo16)
{
    const float qscale = 0.17677669529663687f;   // 1/sqrt(32)
    if (blockIdx.x == 4096){
        int t = threadIdx.x;
        #pragma unroll
        for (int e = 0; e < 8; ++e){
            int idx = t*8 + e;              // 0..1023
            int ee = idx & 7, nn = (idx >> 3) & 15, gg = (idx >> 7) & 3, ch = (idx >> 9) & 1;
            int k = ch*32 + gg*8 + ee;
            float wv = lng[k] * ((nn < 8) ? Wp[k*8 + nn] : Wpg[k*8 + (nn-8)]);
            gwb16[idx] = f2bf(wv);
        }
        if (t < 32){
            int c = t & 15;
            float acc2 = 0.f;
            for (int p = 0; p < 64; ++p){
                float wv = (c < 8) ? Wp[p*8+c] : Wpg[p*8+(c-8)];
                acc2 += wv * ((t < 16) ? lng[p] : lnb[p]);
            }
            gac[t] = acc2;                  // [0..15]=A, [16..31]=C
        }
        return;
    }
    if (blockIdx.x >= 4609){
        // Wo conversion -> B-frag layout wo16[((ks*4+grp)*512 + n)*8 + e], k = ks*32+grp*8+e
        int wb = blockIdx.x - 4609;         // 0..127
        int t = threadIdx.x;
        int idx0 = wb*1024 + t*8;
        int n = (idx0 >> 3) & 511, grp = (idx0 >> 12) & 3, ks = idx0 >> 14;
        int kb = ks*32 + grp*8;
        u16 outv[8];
        #pragma unroll
        for (int e = 0; e < 8; ++e)
            outv[e] = f2bf(Wo[(size_t)(kb + e)*DD + n]);
        *(uint4*)&wo16[idx0] = *(uint4*)outv;
        return;
    }
    if (blockIdx.x > 4096){
        // W{q,k,v,g} conversion -> wb16[(((z*16+ks)*4+grp)*256 + n)*8 + e]
        int wb = blockIdx.x - 4097;         // 0..511
        int t = threadIdx.x;
        int idx0 = wb*1024 + t*8;
        int n = (idx0 >> 3) & 255, grp = (idx0 >> 11) & 3;
        int ks = (idx0 >> 13) & 15, z = idx0 >> 17;
        const float* Wsrc = (z==0)?Wq : (z==1)?Wk : (z==2)?Wv : Wg;
        int kbase2 = ks*32 + grp*8;
        u16 outv[8];
        #pragma unroll
        for (int e = 0; e < 8; ++e){
            float wv = Wsrc[(size_t)(kbase2 + e)*HC + n];
            if (z == 0) wv *= qscale;
            outv[e] = f2bf(wv);
        }
        *(uint4*)&wb16[idx0] = *(uint4*)outv;
        return;
    }
    int row = blockIdx.x;           // 0..4095
    int side = row >> 11;
    int r = row & 2047;
    const float* x = (side ? xj : xi) + (size_t)r * DD;
    const float* gg = side ? gj : gi;
    const float* bbp = side ? bj : bi;
    int t = threadIdx.x;
    float4 v = ((const float4*)x)[t];
    float s  = v.x + v.y + v.z + v.w;
    float sq = v.x*v.x + v.y*v.y + v.z*v.z + v.w*v.w;
    #pragma unroll
    for (int off = 32; off; off >>= 1){ s += __shfl_down(s, off); sq += __shfl_down(sq, off); }
    __shared__ float ls[2], lq[2];
    int w = t >> 6, lane = t & 63;
    if (lane == 0){ ls[w] = s; lq[w] = sq; }
    __syncthreads();
    s = ls[0] + ls[1]; sq = lq[0] + lq[1];
    float mean = s * (1.0f/DD);
    float var  = sq * (1.0f/DD) - mean*mean;
    float rstd = rsqrtf(var + EPSF);
    float4 gv = ((const float4*)gg)[t];
    float4 bv = ((const float4*)bbp)[t];
    float4 o;
    o.x = (v.x-mean)*rstd*gv.x + bv.x;
    o.y = (v.y-mean)*rstd*gv.y + bv.y;
    o.z = (v.z-mean)*rstd*gv.z + bv.z;
    o.w = (v.w-mean)*rstd*gv.w + bv.w;
    if (!side) ((float4*)(ni + (size_t)r*DD))[t] = o;
    u16* x16 = (side ? nj16 : ni16) + (size_t)r*DD;
    uint2 pk; pk.x = pk2(o.x, o.y); pk.y = pk2(o.z, o.w);
    *(uint2*)&x16[t*4] = pk;
}

// ---------------- K2: combo — bias (quarter-rows, MFMA stream) + proj (MFMA GEMM) ----------------
// sc layout: [bi][jblk = j/16][h][j%16]
// grid 8704: n%17==16 -> proj (512), else bias quarter-row (8192): bi = id>>2, qtr = id&3
__global__ __launch_bounds__(256) void combo_kernel(
    const float* __restrict__ pe, const float* __restrict__ pmask,
    const u16* __restrict__ gwb16, const float* __restrict__ gac,
    const float* __restrict__ bp, const float* __restrict__ bpg,
    u16* __restrict__ sc,
    const u16* __restrict__ ni16, const u16* __restrict__ nj16,
    const u16* __restrict__ wb16, const float* __restrict__ bg,
    u16* __restrict__ qbf, u16* __restrict__ kbf,
    u16* __restrict__ vT, float* __restrict__ g)
{
    int n = blockIdx.x;
    int q17 = n / 17, r17 = n - q17*17;
    int t = threadIdx.x;
    int wid = t >> 6, lane = t & 63;
    int ln15 = lane & 15, grp = lane >> 4;
    const f32x4 zeroc = {0.f,0.f,0.f,0.f};

    if (r17 != 16){
        // ---------- bias body: 256 j's per block (4 tiles/wave) ----------
        int id = n - q17;                          // 0..8191
        int bi = id >> 2, qtr = id & 3;
        const size_t peRow = (size_t)bi * JJ * PP;
        int r4 = lane >> 2, q4 = lane & 3;
        int jbase = qtr*256 + wid*64;              // this wave's 64 j's
        short8 bf0 = ld_frag16(gwb16 + ((0*4 + grp)*16 + ln15)*8);
        short8 bf1 = ld_frag16(gwb16 + ((1*4 + grp)*16 + ln15)*8);
        float Acoef = gac[ln15];
        float Ccoef = gac[16 + ln15];
        float bpv  = bp[ln15 & 7];
        float bpgv = bpg[ln15 & 7];
        size_t scb = (size_t)bi * 8192;            // bi * (JJ/16) * 128
        const float* wbase = pe + peRow + (size_t)jbase * PP + r4*64 + q4*4;
        const float* mbase = pmask + (size_t)bi*JJ + jbase + r4;
        int selg = grp >> 1;
        int idx0 = 4*ln15 + 2*(grp & 1);

        for (int tile = 0; tile < 4; ++tile){
            const float* pt = wbase + (size_t)tile*1024;
            f4v F0 = ntld4(pt + 0);
            f4v F1 = ntld4(pt + 16);
            f4v F2 = ntld4(pt + 32);
            f4v F3 = ntld4(pt + 48);
            float pmv = mbase[tile*16];
            float s  = (F0.x+F0.y+F0.z+F0.w) + (F1.x+F1.y+F1.z+F1.w)
                     + (F2.x+F2.y+F2.z+F2.w) + (F3.x+F3.y+F3.z+F3.w);
            float sq = F0.x*F0.x+F0.y*F0.y+F0.z*F0.z+F0.w*F0.w
                     + F1.x*F1.x+F1.y*F1.y+F1.z*F1.z+F1.w*F1.w
                     + F2.x*F2.x+F2.y*F2.y+F2.z*F2.z+F2.w*F2.w
                     + F3.x*F3.x+F3.y*F3.y+F3.z*F3.z+F3.w*F3.w;
            s  += __shfl_xor(s, 1);  s  += __shfl_xor(s, 2);
            sq += __shfl_xor(sq, 1); sq += __shfl_xor(sq, 2);
            u32 W00 = pk2(F0.x,F0.y), W01 = pk2(F0.z,F0.w);
            u32 W10 = pk2(F1.x,F1.y), W11 = pk2(F1.z,F1.w);
            u32 W20 = pk2(F2.x,F2.y), W21 = pk2(F2.z,F2.w);
            u32 W30 = pk2(F3.x,F3.y), W31 = pk2(F3.z,F3.w);
            u32 Wa0 = selg ? W10 : W00, Wa1 = selg ? W11 : W01;
            u32 Wb0 = selg ? W30 : W20, Wb1 = selg ? W31 : W21;
            u32 aw[4];
            aw[0] = __shfl(Wa0, idx0);     aw[1] = __shfl(Wa1, idx0);
            aw[2] = __shfl(Wa0, idx0 + 1); aw[3] = __shfl(Wa1, idx0 + 1);
            short8 a0; __builtin_memcpy(&a0, aw, 16);
            aw[0] = __shfl(Wb0, idx0);     aw[1] = __shfl(Wb1, idx0);
            aw[2] = __shfl(Wb0, idx0 + 1); aw[3] = __shfl(Wb1, idx0 + 1);
            short8 a1; __builtin_memcpy(&a1, aw, 16);
            f32x4 acc = MFMA16(a0, bf0, zeroc);
            acc = MFMA16(a1, bf1, acc);        // acc[r] = S[jbase+tile*16+grp*4+r][c=ln15]
            float pbq[4];
            #pragma unroll
            for (int r = 0; r < 4; ++r){
                int sl = 16*grp + 4*r;
                float mean = __shfl(s,  sl) * (1.0f/PP);
                float msq  = __shfl(sq, sl) * (1.0f/PP);
                float rstd = rsqrtf(msq - mean*mean + EPSF);
                float afull = rstd*(acc[r] - mean*Acoef) + Ccoef;
                float other = __shfl_xor(afull, 8);
                float mbv = INFF * (__shfl(pmv, sl) - 1.0f);
                pbq[r] = (afull + bpv) * sigmoidf_(other + bpgv) + mbv;
            }
            if (ln15 < 8){
                int jblk = (jbase >> 4) + tile;
                uint2 st;
                st.x = pk2(pbq[0], pbq[1]);
                st.y = pk2(pbq[2], pbq[3]);
                *(uint2*)&sc[scb + (size_t)jblk*128 + ln15*16 + grp*4] = st;
            }
        }
    } else {
        // ---------- proj body: MFMA GEMM, no LDS, no barriers ----------
        int pid = q17;                             // 0..511
        int z = pid & 3, ct = (pid >> 2) & 3, rt = pid >> 4;
        const u16* X16 = (z==1 || z==2) ? nj16 : ni16;
        int row0 = rt*64, c0 = ct*64;
        int rowb = row0 + wid*16;
        const u16* xrow = X16 + (size_t)(rowb + ln15)*DD;
        const u16* wz = wb16 + (size_t)z*16*4*256*8;
        f32x4 acc0 = zeroc, acc1 = zeroc, acc2 = zeroc, acc3 = zeroc;
        for (int ks = 0; ks < 16; ++ks){
            short8 af = ld_frag16(xrow + ks*32 + grp*8);
            const u16* wk2 = wz + ((size_t)(ks*4 + grp)*256)*8;
            short8 b0 = ld_frag16(wk2 + (c0 + 0*16 + ln15)*8);
            short8 b1 = ld_frag16(wk2 + (c0 + 1*16 + ln15)*8);
            short8 b2 = ld_frag16(wk2 + (c0 + 2*16 + ln15)*8);
            short8 b3 = ld_frag16(wk2 + (c0 + 3*16 + ln15)*8);
            acc0 = MFMA16(af, b0, acc0);
            acc1 = MFMA16(af, b1, acc1);
            acc2 = MFMA16(af, b2, acc2);
            acc3 = MFMA16(af, b3, acc3);
        }
        int b = rowb >> 10, ij0 = (rowb & 1023) + grp*4;
        if (z == 2){
            #pragma unroll
            for (int cf = 0; cf < 4; ++cf){
                f32x4 a = (cf==0)?acc0:(cf==1)?acc1:(cf==2)?acc2:acc3;
                int chc = c0 + cf*16 + ln15;
                int h = chc >> 5, c = chc & 31;
                uint2 st;
                st.x = pk2(a[0], a[1]);
                st.y = pk2(a[2], a[3]);
                *(uint2*)&vT[((size_t)(b*HH + h)*CC + c)*JJ + ij0] = st;
            }
        } else if (z == 3){
            float bgv[4];
            #pragma unroll
            for (int cf = 0; cf < 4; ++cf) bgv[cf] = bg[c0 + cf*16 + ln15];
            #pragma unroll
            for (int cf = 0; cf < 4; ++cf){
                f32x4 a = (cf==0)?acc0:(cf==1)?acc1:(cf==2)?acc2:acc3;
                int chc = c0 + cf*16 + ln15;
                #pragma unroll
                for (int r = 0; r < 4; ++r){
                    int row = rowb + grp*4 + r;
                    g[(size_t)row*HC + chc] = sigmoidf_(a[r] + bgv[cf]);
                }
            }
        } else {
            u16* dstb = (z == 0) ? qbf : kbf;
            #pragma unroll
            for (int cf = 0; cf < 4; ++cf){
                f32x4 a = (cf==0)?acc0:(cf==1)?acc1:(cf==2)?acc2:acc3;
                int chc = c0 + cf*16 + ln15;
                int h = chc >> 5, c = chc & 31;
                #pragma unroll
                for (int r = 0; r < 4; ++r){
                    dstb[((size_t)(b*HH + h)*II + ij0 + r)*CC + c] = f2bf(a[r]);
                }
            }
        }
    }
}

// ---------------- K3: fused flash attention (parallel 4-wave epilogue, bf16 o) ----------------
__global__ __launch_bounds__(256) void fattn_kernel(
    const u16* __restrict__ qbf, const u16* __restrict__ kbf,
    const u16* __restrict__ vT, const u16* __restrict__ sc,
    const float* __restrict__ g, u16* __restrict__ o16)
{
    int it = blockIdx.x, h = blockIdx.y, b = blockIdx.z;
    int t = threadIdx.x;
    int w = t >> 6, lane = t & 63;       // jw = w (0..3)
    int ln15 = lane & 15, grp = lane >> 4;
    int i0 = it*16;
    size_t bh = (size_t)(b*HH + h);

    short8 qf = ld_frag16(qbf + (bh*II + i0 + ln15)*CC + grp*8);
    const u16* kbase = kbf + bh*JJ*CC;
    const u16* vbase = vT + bh*CC*JJ;
    // sc layout [i][jblk][h][jw]: per-row base + head offset
    size_t scb = (size_t)(b*II + i0 + ln15) * 8192 + h*16;

    f32x4 oacc0 = {0.f,0.f,0.f,0.f}, oacc1 = {0.f,0.f,0.f,0.f};
    float m = -INFINITY, l = 0.f;
    const f32x4 zeroc = {0.f,0.f,0.f,0.f};

    for (int ch = 0; ch < 8; ++ch){
        int j0 = (ch*4 + w)*32;
        int jb = j0 >> 4;
        short8 ka0 = ld_frag16(kbase + (size_t)(j0 + ln15)*CC + grp*8);
        short8 ka1 = ld_frag16(kbase + (size_t)(j0 + 16 + ln15)*CC + grp*8);
        f32x4 s0 = MFMA16(ka0, qf, zeroc);   // S[j0+grp*4+r][i0+ln15]
        f32x4 s1 = MFMA16(ka1, qf, zeroc);
        uint2 b0 = *(const uint2*)&sc[scb + (size_t)jb*128 + grp*4];
        uint2 b1 = *(const uint2*)&sc[scb + (size_t)(jb+1)*128 + grp*4];
        float s[8];
        s[0] = s0[0] + bf16lo(b0.x); s[1] = s0[1] + bf16hi(b0.x);
        s[2] = s0[2] + bf16lo(b0.y); s[3] = s0[3] + bf16hi(b0.y);
        s[4] = s1[0] + bf16lo(b1.x); s[5] = s1[1] + bf16hi(b1.x);
        s[6] = s1[2] + bf16lo(b1.y); s[7] = s1[3] + bf16hi(b1.y);
        float pm = s[0];
        #pragma unroll
        for (int e = 1; e < 8; ++e) pm = fmaxf(pm, s[e]);
        pm = fmaxf(pm, __shfl_xor(pm, 16));
        pm = fmaxf(pm, __shfl_xor(pm, 32));
        float mn = fmaxf(m, pm);
        float alpha = __expf(m - mn);
        m = mn;
        float p[8], psum = 0.f;
        #pragma unroll
        for (int e = 0; e < 8; ++e){ p[e] = __expf(s[e] - m); psum += p[e]; }
        l = l*alpha + psum;
        #pragma unroll
        for (int r = 0; r < 4; ++r){
            float ar = __shfl(alpha, grp*4 + r);
            oacc0[r] *= ar; oacc1[r] *= ar;
        }
        u32 pw[4];
        pw[0] = pk2(p[0], p[1]); pw[1] = pk2(p[2], p[3]);
        pw[2] = pk2(p[4], p[5]); pw[3] = pk2(p[6], p[7]);
        short8 pa; __builtin_memcpy(&pa, pw, 16);
        const u16* vr0 = vbase + (size_t)(ln15)*JJ + j0 + grp*4;
        const u16* vr1 = vbase + (size_t)(16 + ln15)*JJ + j0 + grp*4;
        uint2 va0 = *(const uint2*)vr0, va1 = *(const uint2*)(vr0 + 16);
        u32 vw[4] = {va0.x, va0.y, va1.x, va1.y};
        short8 vb0; __builtin_memcpy(&vb0, vw, 16);
        uint2 vc0 = *(const uint2*)vr1, vc1 = *(const uint2*)(vr1 + 16);
        u32 vx[4] = {vc0.x, vc0.y, vc1.x, vc1.y};
        short8 vb1; __builtin_memcpy(&vb1, vx, 16);
        oacc0 = MFMA16(pa, vb0, oacc0);
        oacc1 = MFMA16(pa, vb1, oacc1);
    }
    l += __shfl_xor(l, 16); l += __shfl_xor(l, 32);

    __shared__ float mb[4][64], lb[4][64], ob[4][8][64];
    mb[w][lane] = m; lb[w][lane] = l;
    #pragma unroll
    for (int r = 0; r < 4; ++r){ ob[w][r][lane] = oacc0[r]; ob[w][4+r][lane] = oacc1[r]; }
    __syncthreads();
    {
        int r = w;                           // each wave merges one r (4x parallel)
        int row = grp*4 + r;                 // 0..15
        float M = fmaxf(fmaxf(mb[0][row], mb[1][row]), fmaxf(mb[2][row], mb[3][row]));
        float sw[4], L = 0.f;
        #pragma unroll
        for (int w2 = 0; w2 < 4; ++w2){
            sw[w2] = __expf(mb[w2][row] - M);
            L += lb[w2][row] * sw[w2];
        }
        float inv = 1.0f / L;
        float o0 = 0.f, o1 = 0.f;
        #pragma unroll
        for (int w2 = 0; w2 < 4; ++w2){
            o0 += ob[w2][r][lane]   * sw[w2];
            o1 += ob[w2][4+r][lane] * sw[w2];
        }
        size_t rb = (size_t)(b*II + i0 + row)*HC + h*CC;
        o16[rb + ln15]      = f2bf(o0 * inv * g[rb + ln15]);
        o16[rb + 16 + ln15] = f2bf(o1 * inv * g[rb + 16 + ln15]);
    }
}

// ---------------- K4: out = ni + (o16 @ Wo + bo) * mask  (MFMA, LDS-free) ----------------
__global__ __launch_bounds__(256) void out_mfma(
    const u16* __restrict__ o16, const u16* __restrict__ wo16,
    const float* __restrict__ bo, const float* __restrict__ ni,
    const float* __restrict__ nmask, float* __restrict__ out)
{
    int rt = blockIdx.x, ct = blockIdx.y;      // 32 x 8
    int t = threadIdx.x;
    int wid = t >> 6, lane = t & 63;
    int ln15 = lane & 15, grp = lane >> 4;
    const f32x4 zeroc = {0.f,0.f,0.f,0.f};
    int rowb = rt*64 + wid*16, c0 = ct*64;
    const u16* xrow = o16 + (size_t)(rowb + ln15)*HC;
    f32x4 acc0 = zeroc, acc1 = zeroc, acc2 = zeroc, acc3 = zeroc;
    for (int ks = 0; ks < 8; ++ks){
        short8 af = ld_frag16(xrow + ks*32 + grp*8);
        const u16* wk2 = wo16 + ((size_t)(ks*4 + grp)*DD)*8;
        short8 b0 = ld_frag16(wk2 + (c0 + 0*16 + ln15)*8);
        short8 b1 = ld_frag16(wk2 + (c0 + 1*16 + ln15)*8);
        short8 b2 = ld_frag16(wk2 + (c0 + 2*16 + ln15)*8);
        short8 b3 = ld_frag16(wk2 + (c0 + 3*16 + ln15)*8);
        acc0 = MFMA16(af, b0, acc0);
        acc1 = MFMA16(af, b1, acc1);
        acc2 = MFMA16(af, b2, acc2);
        acc3 = MFMA16(af, b3, acc3);
    }
    float msk[4], niv;
    #pragma unroll
    for (int r = 0; r < 4; ++r) msk[r] = nmask[rowb + grp*4 + r];
    #pragma unroll
    for (int cf = 0; cf < 4; ++cf){
        f32x4 a = (cf==0)?acc0:(cf==1)?acc1:(cf==2)?acc2:acc3;
        int chc = c0 + cf*16 + ln15;
        float bov = bo[chc];
        #pragma unroll
        for (int r = 0; r < 4; ++r){
            int row = rowb + grp*4 + r;
            niv = ni[(size_t)row*DD + chc];
            out[(size_t)row*DD + chc] = (a[r] + bov)*msk[r] + niv;
        }
    }
}

extern "C" void kernel_launch(void* const* d_in, const int* in_sizes, int n_in,
                              void* d_out, int out_size, void* d_ws, size_t ws_size,
                              hipStream_t stream)
{
    const float* node_i = (const float*)d_in[0];
    const float* node_j = (const float*)d_in[1];
    const float* pe     = (const float*)d_in[2];
    const float* pmask  = (const float*)d_in[3];
    const float* nmask  = (const float*)d_in[4];
    const float* ln_i_g = (const float*)d_in[5];
    const float* ln_i_b = (const float*)d_in[6];
    const float* ln_j_g = (const float*)d_in[7];
    const float* ln_j_b = (const float*)d_in[8];
    const float* ln_p_g = (const float*)d_in[9];
    const float* ln_p_b = (const float*)d_in[10];
    const float* Wp     = (const float*)d_in[11];
    const float* bp     = (const float*)d_in[12];
    const float* Wpg    = (const float*)d_in[13];
    const float* bpg    = (const float*)d_in[14];
    const float* Wq     = (const float*)d_in[15];
    const float* Wk     = (const float*)d_in[16];
    const float* Wv     = (const float*)d_in[17];
    const float* Wg     = (const float*)d_in[18];
    const float* bg     = (const float*)d_in[19];
    const float* Wo     = (const float*)d_in[20];
    const float* bo     = (const float*)d_in[21];
    float* out = (float*)d_out;

    char* ws = (char*)d_ws;
    float* ni    = (float*)(ws + 0);                     // 4 MB  (f32, residual)
    u16*   ni16  = (u16*)  (ws + ((size_t)4<<20));       // 2 MB
    u16*   nj16  = (u16*)  (ws + ((size_t)6<<20));       // 2 MB
    u16*   qbf   = (u16*)  (ws + ((size_t)8<<20));       // 1 MB
    u16*   kbf   = (u16*)  (ws + ((size_t)9<<20));       // 1 MB
    u16*   vTb   = (u16*)  (ws + ((size_t)10<<20));      // 1 MB
    u16*   gwb16 = (u16*)  (ws + ((size_t)11<<20));      // 2 KB
    float* gac   = (float*)(ws + ((size_t)11<<20) + 4096); // 128 B
    u16*   wb16  = (u16*)  (ws + ((size_t)12<<20));      // 1 MB
    u16*   wo16  = (u16*)  (ws + ((size_t)13<<20));      // 256 KB
    float* g     = (float*)(ws + ((size_t)14<<20));      // 2 MB
    u16*   o16   = (u16*)  (ws + ((size_t)16<<20));      // 1 MB
    u16*   sc    = (u16*)  (ws + ((size_t)18<<20));      // 32 MB

    ln_kernel<<<dim3(4737), dim3(128), 0, stream>>>(
        node_i, node_j, ln_i_g, ln_i_b, ln_j_g, ln_j_b,
        ln_p_g, ln_p_b, Wp, Wpg, Wq, Wk, Wv, Wg, Wo,
        ni, ni16, nj16, gwb16, gac, wb16, wo16);
    combo_kernel<<<dim3(8704), dim3(256), 0, stream>>>(
        pe, pmask, gwb16, gac, bp, bpg, sc,
        ni16, nj16, wb16, bg, qbf, kbf, vTb, g);
    fattn_kernel<<<dim3(64,8,2), dim3(256), 0, stream>>>(qbf, kbf, vTb, sc, g, o16);
    out_mfma<<<dim3(32,8), dim3(256), 0, stream>>>(o16, wo16, bo, ni, nmask, out);
}